// Round 2
// baseline (1719.780 us; speedup 1.0000x reference)
//
#include <hip/hip_runtime.h>
#include <hip/hip_bf16.h>
#include <math.h>

typedef __hip_bfloat16 bf16;
typedef __attribute__((ext_vector_type(8))) short short8;
typedef __attribute__((ext_vector_type(4))) float floatx4;

static constexpr int TOK = 32768;
static constexpr int CDIM = 384;
static constexpr int HID = 1536;

__device__ __forceinline__ bf16 f2bf(float v) { return __float2bfloat16(v); }

__device__ __forceinline__ void unpack8(uint4 u, float* f) {
  f[0] = __uint_as_float(u.x << 16); f[1] = __uint_as_float(u.x & 0xffff0000u);
  f[2] = __uint_as_float(u.y << 16); f[3] = __uint_as_float(u.y & 0xffff0000u);
  f[4] = __uint_as_float(u.z << 16); f[5] = __uint_as_float(u.z & 0xffff0000u);
  f[6] = __uint_as_float(u.w << 16); f[7] = __uint_as_float(u.w & 0xffff0000u);
}

__device__ __forceinline__ unsigned short bf_bits(float a) {
  bf16 h = __float2bfloat16(a);
  unsigned short u;
  __builtin_memcpy(&u, &h, 2);
  return u;
}
__device__ __forceinline__ unsigned pack2(float a, float b) {
  return (unsigned)bf_bits(a) | ((unsigned)bf_bits(b) << 16);
}

// async global -> LDS, 16 bytes per lane. LDS dest = wave-uniform base + lane*16.
typedef const __attribute__((address_space(1))) unsigned gas_t;
typedef __attribute__((address_space(3))) unsigned las_t;
__device__ __forceinline__ void gload16(const bf16* g, const bf16* l) {
  __builtin_amdgcn_global_load_lds((gas_t*)g, (las_t*)l, 16, 0, 0);
}

// ---------------- weight fp32 -> bf16 transposed ----------------
__global__ void k_convt(const float* __restrict__ src, bf16* __restrict__ dst,
                        int Kd, int Nd) {
  int tid = blockIdx.x * 256 + threadIdx.x;
  if (tid >= Kd * Nd) return;
  int k = tid / Nd, n = tid - k * Nd;
  dst[(size_t)n * Kd + k] = f2bf(src[tid]);
}

// ---------------- LN1 + shift + window partition (4 tokens/block) -----------
__global__ __launch_bounds__(256) void k_ln1(const float* __restrict__ x,
                                             const float* __restrict__ g,
                                             const float* __restrict__ b,
                                             bf16* __restrict__ out) {
  int wt = blockIdx.x * 4 + (threadIdx.x >> 6);
  int lane = threadIdx.x & 63;
  int win = wt >> 6, ntok = wt & 63;
  int bimg = win >> 4, wi = win & 15;
  int sh = (((wi >> 2) << 3) + (ntok >> 3) + 4) & 31;
  int sw = (((wi & 3) << 3) + (ntok & 7) + 4) & 31;
  const float* xr = x + ((size_t)bimg * 1024 + sh * 32 + sw) * CDIM;
  float v[6]; float s = 0.f, ss = 0.f;
#pragma unroll
  for (int j = 0; j < 6; ++j) {
    float t = xr[j * 64 + lane];
    v[j] = t; s += t; ss += t * t;
  }
#pragma unroll
  for (int off = 32; off > 0; off >>= 1) {
    s += __shfl_xor(s, off, 64);
    ss += __shfl_xor(ss, off, 64);
  }
  float mu = s * (1.f / 384.f);
  float var = ss * (1.f / 384.f) - mu * mu;
  float rs = rsqrtf(var + 1e-5f);
  bf16* orow = out + (size_t)wt * CDIM;
#pragma unroll
  for (int j = 0; j < 6; ++j) {
    int c = j * 64 + lane;
    orow[c] = f2bf((v[j] - mu) * rs * g[c] + b[c]);
  }
}

// ---------------- LN2 (normal token order, 4 tokens/block) ------------------
__global__ __launch_bounds__(256) void k_ln2(const float* __restrict__ x1,
                                             const float* __restrict__ g,
                                             const float* __restrict__ b,
                                             bf16* __restrict__ out) {
  int t = blockIdx.x * 4 + (threadIdx.x >> 6);
  int lane = threadIdx.x & 63;
  const float* xr = x1 + (size_t)t * CDIM;
  float v[6]; float s = 0.f, ss = 0.f;
#pragma unroll
  for (int j = 0; j < 6; ++j) {
    float q = xr[j * 64 + lane];
    v[j] = q; s += q; ss += q * q;
  }
#pragma unroll
  for (int off = 32; off > 0; off >>= 1) {
    s += __shfl_xor(s, off, 64);
    ss += __shfl_xor(ss, off, 64);
  }
  float mu = s * (1.f / 384.f);
  float var = ss * (1.f / 384.f) - mu * mu;
  float rs = rsqrtf(var + 1e-5f);
  bf16* orow = out + (size_t)t * CDIM;
#pragma unroll
  for (int j = 0; j < 6; ++j) {
    int c = j * 64 + lane;
    orow[c] = f2bf((v[j] - mu) * rs * g[c] + b[c]);
  }
}

// ============ m97-style GEMM: 128x128 tile, BK=32, global_load_lds ==========
// A [M][K] bf16 row-major; Bt [N][K] bf16 row-major. 256 thr = 4 waves, each
// computes 64x64 (4x4 of 16x16x32 MFMA). Epilogue via padded LDS transpose.
// EPI: 0=QKV scatter, 1=proj(+reverse+shortcut->f32), 2=FC1(+GELU->bf16),
//      3=FC2(+residual->f32)
template <int K, int EPI>
__global__ __launch_bounds__(256) void k_gemm(const bf16* __restrict__ A,
                                              const bf16* __restrict__ Bt,
                                              const float* __restrict__ bias,
                                              const float* __restrict__ extra,
                                              void* __restrict__ outp) {
  __shared__ __attribute__((aligned(16))) bf16 As[128 * 32];
  __shared__ __attribute__((aligned(16))) bf16 Bs[128 * 32];
  __shared__ __attribute__((aligned(16))) float eps[4][16][68];

  const int tid = threadIdx.x;
  const int wv = tid >> 6, lane = tid & 63;
  const int mblk = blockIdx.x * 128, nblk = blockIdx.y * 128;

  // staging: chunk c = wv*2+i covers rows c*16..c*16+15 of the tile
  const int srow = lane >> 2;
  const int skoff = (lane & 3) * 8;
  const bf16* ga0 = A + (size_t)(mblk + wv * 32 + srow) * K + skoff;
  const bf16* ga1 = ga0 + (size_t)16 * K;
  const bf16* gb0 = Bt + (size_t)(nblk + wv * 32 + srow) * K + skoff;
  const bf16* gb1 = gb0 + (size_t)16 * K;
  const bf16* lA0 = As + (wv * 2) * 512;
  const bf16* lA1 = As + (wv * 2 + 1) * 512;
  const bf16* lB0 = Bs + (wv * 2) * 512;
  const bf16* lB1 = Bs + (wv * 2 + 1) * 512;

  const int wr = wv >> 1, wc = wv & 1;
  const int mr = lane & 15, q = lane >> 4;
  const bf16* fa = As + (wr * 64 + mr) * 32 + q * 8;
  const bf16* fb = Bs + (wc * 64 + mr) * 32 + q * 8;

  floatx4 acc[4][4];
#pragma unroll
  for (int i = 0; i < 4; ++i)
#pragma unroll
    for (int j = 0; j < 4; ++j) acc[i][j] = floatx4{0.f, 0.f, 0.f, 0.f};

  for (int k0 = 0; k0 < K; k0 += 32) {
    __syncthreads();
    gload16(ga0 + k0, lA0);
    gload16(ga1 + k0, lA1);
    gload16(gb0 + k0, lB0);
    gload16(gb1 + k0, lB1);
    __syncthreads();
    short8 a[4], b[4];
#pragma unroll
    for (int mt = 0; mt < 4; ++mt) a[mt] = *(const short8*)(fa + mt * 512);
#pragma unroll
    for (int nt = 0; nt < 4; ++nt) b[nt] = *(const short8*)(fb + nt * 512);
#pragma unroll
    for (int mt = 0; mt < 4; ++mt)
#pragma unroll
      for (int nt = 0; nt < 4; ++nt)
        acc[mt][nt] = __builtin_amdgcn_mfma_f32_16x16x32_bf16(a[mt], b[nt], acc[mt][nt], 0, 0, 0);
  }

  // ---------------- epilogue: per-wave LDS transpose ----------------
  const int rr = lane >> 2, c0 = (lane & 3) * 16;
#pragma unroll 1
  for (int mt = 0; mt < 4; ++mt) {
#pragma unroll
    for (int nt = 0; nt < 4; ++nt)
#pragma unroll
      for (int r = 0; r < 4; ++r)
        eps[wv][q * 4 + r][nt * 16 + mr] = acc[mt][nt][r];
    // wave-private region; compiler inserts lgkmcnt wait for the alias
    float v[16];
#pragma unroll
    for (int j = 0; j < 4; ++j) {
      float4 t = *(const float4*)&eps[wv][rr][c0 + j * 4];
      v[j * 4 + 0] = t.x; v[j * 4 + 1] = t.y; v[j * 4 + 2] = t.z; v[j * 4 + 3] = t.w;
    }
    const int grow = mblk + wr * 64 + mt * 16 + rr;
    const int gcol = nblk + wc * 64 + c0;

    if constexpr (EPI == 0) {
      // QKV scatter: col -> (s,h,d); rows are window tokens
      int win = grow >> 6, ntok = grow & 63;
      int s = gcol / 384;
      int rem = gcol - s * 384;
      int h = rem >> 5, d0 = rem & 31;  // d0 in {0,16}
      bf16* op = (bf16*)outp + (((size_t)s * 512 + win) * 12 + h) * 2048 + ntok * 32 + d0;
      uint4 pk;
      float bv[16];
#pragma unroll
      for (int j = 0; j < 16; ++j) bv[j] = v[j] + bias[gcol + j];
      pk.x = pack2(bv[0], bv[1]); pk.y = pack2(bv[2], bv[3]);
      pk.z = pack2(bv[4], bv[5]); pk.w = pack2(bv[6], bv[7]);
      *(uint4*)op = pk;
      pk.x = pack2(bv[8], bv[9]); pk.y = pack2(bv[10], bv[11]);
      pk.z = pack2(bv[12], bv[13]); pk.w = pack2(bv[14], bv[15]);
      *(uint4*)(op + 8) = pk;
    } else if constexpr (EPI == 1) {
      // proj: window-reverse + unshift + shortcut -> fp32 x1
      int win = grow >> 6, ntok = grow & 63;
      int bimg = win >> 4, wi = win & 15;
      int hh = (((wi >> 2) << 3) + (ntok >> 3) + 4) & 31;
      int ww = (((wi & 3) << 3) + (ntok & 7) + 4) & 31;
      size_t t = (size_t)bimg * 1024 + hh * 32 + ww;
      float* op = (float*)outp + t * CDIM + gcol;
      const float* xr = extra + t * CDIM + gcol;
#pragma unroll
      for (int j = 0; j < 4; ++j) {
        float4 xv = *(const float4*)(xr + j * 4);
        float4 ov;
        ov.x = xv.x + v[j * 4 + 0] + bias[gcol + j * 4 + 0];
        ov.y = xv.y + v[j * 4 + 1] + bias[gcol + j * 4 + 1];
        ov.z = xv.z + v[j * 4 + 2] + bias[gcol + j * 4 + 2];
        ov.w = xv.w + v[j * 4 + 3] + bias[gcol + j * 4 + 3];
        *(float4*)(op + j * 4) = ov;
      }
    } else if constexpr (EPI == 2) {
      // FC1: bias + GELU -> bf16
      float gv[16];
#pragma unroll
      for (int j = 0; j < 16; ++j) {
        float z = v[j] + bias[gcol + j];
        float u = 0.7978845608028654f * (z + 0.044715f * z * z * z);
        gv[j] = z / (1.f + __expf(-2.f * u));
      }
      bf16* op = (bf16*)outp + (size_t)grow * HID + gcol;
      uint4 pk;
      pk.x = pack2(gv[0], gv[1]); pk.y = pack2(gv[2], gv[3]);
      pk.z = pack2(gv[4], gv[5]); pk.w = pack2(gv[6], gv[7]);
      *(uint4*)op = pk;
      pk.x = pack2(gv[8], gv[9]); pk.y = pack2(gv[10], gv[11]);
      pk.z = pack2(gv[12], gv[13]); pk.w = pack2(gv[14], gv[15]);
      *(uint4*)(op + 8) = pk;
    } else {
      // FC2: bias + residual -> fp32 out
      float* op = (float*)outp + (size_t)grow * CDIM + gcol;
      const float* xr = extra + (size_t)grow * CDIM + gcol;
#pragma unroll
      for (int j = 0; j < 4; ++j) {
        float4 xv = *(const float4*)(xr + j * 4);
        float4 ov;
        ov.x = xv.x + v[j * 4 + 0] + bias[gcol + j * 4 + 0];
        ov.y = xv.y + v[j * 4 + 1] + bias[gcol + j * 4 + 1];
        ov.z = xv.z + v[j * 4 + 2] + bias[gcol + j * 4 + 2];
        ov.w = xv.w + v[j * 4 + 3] + bias[gcol + j * 4 + 3];
        *(float4*)(op + j * 4) = ov;
      }
    }
  }
}

// ---------------- attention: 1 wave per (window, head) ----------------------
__global__ __launch_bounds__(64) void k_attn(const bf16* __restrict__ qkv,
                                             const float* __restrict__ tblg,
                                             bf16* __restrict__ out) {
  __shared__ __attribute__((aligned(16))) float ks[64][32];
  __shared__ __attribute__((aligned(16))) float vs[64][32];
  __shared__ float tbl[2700];
  __shared__ int rids[64];
  int bid = blockIdx.x;
  int win = bid / 12, head = bid - win * 12;
  int lane = threadIdx.x;
  for (int i = lane; i < 2700; i += 64) tbl[i] = tblg[i];

  size_t base = ((size_t)win * 12 + head) * 2048 + lane * 32;
  const uint4* qp = (const uint4*)(qkv + base);
  const uint4* kp = (const uint4*)(qkv + (size_t)12582912 + base);
  const uint4* vp = (const uint4*)(qkv + (size_t)25165824 + base);

  float qreg[32];
#pragma unroll
  for (int i = 0; i < 4; ++i) { uint4 u = qp[i]; unpack8(u, qreg + i * 8); }
#pragma unroll
  for (int i = 0; i < 4; ++i) {
    uint4 u = kp[i]; float f[8]; unpack8(u, f);
#pragma unroll
    for (int j = 0; j < 8; ++j) ks[lane][i * 8 + j] = f[j];
  }
#pragma unroll
  for (int i = 0; i < 4; ++i) {
    uint4 u = vp[i]; float f[8]; unpack8(u, f);
#pragma unroll
    for (int j = 0; j < 8; ++j) vs[lane][i * 8 + j] = f[j];
  }
  int wi = win & 15;
  int hb = (wi >> 2) << 3, wb = (wi & 3) << 3;
  int r_i = lane >> 3, c_i = lane & 7;
  int rh = hb + r_i, rw = wb + c_i;
  int rid = (rh < 24 ? 0 : (rh < 28 ? 1 : 2)) * 3 + (rw < 24 ? 0 : (rw < 28 ? 1 : 2));
  rids[lane] = rid;
  __syncthreads();

  float s[64];
  float mx = -1e30f;
#pragma unroll
  for (int j = 0; j < 64; ++j) {
    const float4* kr = (const float4*)ks[j];
    float dot = 0.f;
#pragma unroll
    for (int d4 = 0; d4 < 8; ++d4) {
      float4 kk = kr[d4];
      dot += qreg[d4 * 4 + 0] * kk.x;
      dot += qreg[d4 * 4 + 1] * kk.y;
      dot += qreg[d4 * 4 + 2] * kk.z;
      dot += qreg[d4 * 4 + 3] * kk.w;
    }
    int r_j = j >> 3, c_j = j & 7;
    float bias = tbl[((r_i - r_j + 7) * 15 + (c_i - c_j + 7)) * 12 + head];
    float val = dot * 0.17677669529663687f + bias + (rid == rids[j] ? 0.f : -100.f);
    s[j] = val;
    mx = fmaxf(mx, val);
  }
  float l = 0.f;
#pragma unroll
  for (int j = 0; j < 64; ++j) {
    float p = __expf(s[j] - mx);
    s[j] = p;
    l += p;
  }
  float inv = 1.f / l;
  float o[32];
#pragma unroll
  for (int d = 0; d < 32; ++d) o[d] = 0.f;
#pragma unroll
  for (int j = 0; j < 64; ++j) {
    float p = s[j];
    const float4* vr = (const float4*)vs[j];
#pragma unroll
    for (int d4 = 0; d4 < 8; ++d4) {
      float4 vv = vr[d4];
      o[d4 * 4 + 0] += p * vv.x;
      o[d4 * 4 + 1] += p * vv.y;
      o[d4 * 4 + 2] += p * vv.z;
      o[d4 * 4 + 3] += p * vv.w;
    }
  }
  uint4* o4 = (uint4*)(out + ((size_t)win * 64 + lane) * CDIM + head * 32);
#pragma unroll
  for (int i = 0; i < 4; ++i) {
    uint4 pk;
    pk.x = pack2(o[i * 8 + 0] * inv, o[i * 8 + 1] * inv);
    pk.y = pack2(o[i * 8 + 2] * inv, o[i * 8 + 3] * inv);
    pk.z = pack2(o[i * 8 + 4] * inv, o[i * 8 + 5] * inv);
    pk.w = pack2(o[i * 8 + 6] * inv, o[i * 8 + 7] * inv);
    o4[i] = pk;
  }
}

extern "C" void kernel_launch(void* const* d_in, const int* in_sizes, int n_in,
                              void* d_out, int out_size, void* d_ws, size_t ws_size,
                              hipStream_t stream) {
  const float* x = (const float*)d_in[0];
  const float* n1g = (const float*)d_in[1];
  const float* n1b = (const float*)d_in[2];
  const float* qkv_w = (const float*)d_in[3];
  const float* qkv_b = (const float*)d_in[4];
  const float* reltbl = (const float*)d_in[5];
  const float* proj_w = (const float*)d_in[6];
  const float* proj_b = (const float*)d_in[7];
  const float* n2g = (const float*)d_in[8];
  const float* n2b = (const float*)d_in[9];
  const float* fc1_w = (const float*)d_in[10];
  const float* fc1_b = (const float*)d_in[11];
  const float* fc2_w = (const float*)d_in[12];
  const float* fc2_b = (const float*)d_in[13];
  float* out = (float*)d_out;

  char* p = (char*)d_ws;
  bf16* w_qkv_t = (bf16*)p;  p += (size_t)442368 * 2;
  bf16* w_proj_t = (bf16*)p; p += (size_t)147456 * 2;
  bf16* w_fc1_t = (bf16*)p;  p += (size_t)589824 * 2;
  bf16* w_fc2_t = (bf16*)p;  p += (size_t)589824 * 2;
  bf16* bufA = (bf16*)p;     p += (size_t)12582912 * 2;
  bf16* qkvb = (bf16*)p;     p += (size_t)37748736 * 2;
  bf16* attno = (bf16*)p;    p += (size_t)12582912 * 2;
  float* x1 = (float*)p;     p += (size_t)12582912 * 4;
  bf16* hidden = qkvb;  // [T][1536] bf16, reuses dead qkv/attn regions

  k_convt<<<dim3((442368 + 255) / 256), dim3(256), 0, stream>>>(qkv_w, w_qkv_t, 384, 1152);
  k_convt<<<dim3((147456 + 255) / 256), dim3(256), 0, stream>>>(proj_w, w_proj_t, 384, 384);
  k_convt<<<dim3((589824 + 255) / 256), dim3(256), 0, stream>>>(fc1_w, w_fc1_t, 384, 1536);
  k_convt<<<dim3((589824 + 255) / 256), dim3(256), 0, stream>>>(fc2_w, w_fc2_t, 1536, 384);

  k_ln1<<<dim3(8192), dim3(256), 0, stream>>>(x, n1g, n1b, bufA);
  k_gemm<384, 0><<<dim3(256, 9), dim3(256), 0, stream>>>(bufA, w_qkv_t, qkv_b, nullptr, qkvb);
  k_attn<<<dim3(6144), dim3(64), 0, stream>>>(qkvb, reltbl, attno);
  k_gemm<384, 1><<<dim3(256, 3), dim3(256), 0, stream>>>(attno, w_proj_t, proj_b, x, x1);
  k_ln2<<<dim3(8192), dim3(256), 0, stream>>>(x1, n2g, n2b, bufA);
  k_gemm<384, 2><<<dim3(256, 12), dim3(256), 0, stream>>>(bufA, w_fc1_t, fc1_b, nullptr, hidden);
  k_gemm<1536, 3><<<dim3(256, 3), dim3(256), 0, stream>>>(hidden, w_fc2_t, fc2_b, x1, out);
}

// Round 3
// 594.677 us; speedup vs baseline: 2.8920x; 2.8920x over previous
//
#include <hip/hip_runtime.h>
#include <hip/hip_bf16.h>
#include <math.h>

typedef __hip_bfloat16 bf16;
typedef __attribute__((ext_vector_type(8))) short short8;
typedef __attribute__((ext_vector_type(4))) float floatx4;

static constexpr int TOK = 32768;
static constexpr int CDIM = 384;
static constexpr int HID = 1536;

__device__ __forceinline__ bf16 f2bf(float v) { return __float2bfloat16(v); }

__device__ __forceinline__ void unpack8(uint4 u, float* f) {
  f[0] = __uint_as_float(u.x << 16); f[1] = __uint_as_float(u.x & 0xffff0000u);
  f[2] = __uint_as_float(u.y << 16); f[3] = __uint_as_float(u.y & 0xffff0000u);
  f[4] = __uint_as_float(u.z << 16); f[5] = __uint_as_float(u.z & 0xffff0000u);
  f[6] = __uint_as_float(u.w << 16); f[7] = __uint_as_float(u.w & 0xffff0000u);
}

__device__ __forceinline__ unsigned short bf_bits(float a) {
  bf16 h = __float2bfloat16(a);
  unsigned short u;
  __builtin_memcpy(&u, &h, 2);
  return u;
}
__device__ __forceinline__ unsigned pack2(float a, float b) {
  return (unsigned)bf_bits(a) | ((unsigned)bf_bits(b) << 16);
}

// async global -> LDS, 16 bytes per lane. LDS dest = wave-uniform base + lane*16.
typedef const __attribute__((address_space(1))) unsigned gas_t;
typedef __attribute__((address_space(3))) unsigned las_t;
__device__ __forceinline__ void gload16(const bf16* g, const bf16* l) {
  __builtin_amdgcn_global_load_lds((gas_t*)g, (las_t*)l, 16, 0, 0);
}

// ---------------- weight fp32 -> bf16 transposed ----------------
__global__ void k_convt(const float* __restrict__ src, bf16* __restrict__ dst,
                        int Kd, int Nd) {
  int tid = blockIdx.x * 256 + threadIdx.x;
  if (tid >= Kd * Nd) return;
  int k = tid / Nd, n = tid - k * Nd;
  dst[(size_t)n * Kd + k] = f2bf(src[tid]);
}

// ---------------- LN1 + shift + window partition (4 tokens/block) -----------
__global__ __launch_bounds__(256) void k_ln1(const float* __restrict__ x,
                                             const float* __restrict__ g,
                                             const float* __restrict__ b,
                                             bf16* __restrict__ out) {
  int wt = blockIdx.x * 4 + (threadIdx.x >> 6);
  int lane = threadIdx.x & 63;
  int win = wt >> 6, ntok = wt & 63;
  int bimg = win >> 4, wi = win & 15;
  int sh = (((wi >> 2) << 3) + (ntok >> 3) + 4) & 31;
  int sw = (((wi & 3) << 3) + (ntok & 7) + 4) & 31;
  const float* xr = x + ((size_t)bimg * 1024 + sh * 32 + sw) * CDIM;
  float v[6]; float s = 0.f, ss = 0.f;
#pragma unroll
  for (int j = 0; j < 6; ++j) {
    float t = xr[j * 64 + lane];
    v[j] = t; s += t; ss += t * t;
  }
#pragma unroll
  for (int off = 32; off > 0; off >>= 1) {
    s += __shfl_xor(s, off, 64);
    ss += __shfl_xor(ss, off, 64);
  }
  float mu = s * (1.f / 384.f);
  float var = ss * (1.f / 384.f) - mu * mu;
  float rs = rsqrtf(var + 1e-5f);
  bf16* orow = out + (size_t)wt * CDIM;
#pragma unroll
  for (int j = 0; j < 6; ++j) {
    int c = j * 64 + lane;
    orow[c] = f2bf((v[j] - mu) * rs * g[c] + b[c]);
  }
}

// ---------------- LN2 (normal token order, 4 tokens/block) ------------------
__global__ __launch_bounds__(256) void k_ln2(const float* __restrict__ x1,
                                             const float* __restrict__ g,
                                             const float* __restrict__ b,
                                             bf16* __restrict__ out) {
  int t = blockIdx.x * 4 + (threadIdx.x >> 6);
  int lane = threadIdx.x & 63;
  const float* xr = x1 + (size_t)t * CDIM;
  float v[6]; float s = 0.f, ss = 0.f;
#pragma unroll
  for (int j = 0; j < 6; ++j) {
    float q = xr[j * 64 + lane];
    v[j] = q; s += q; ss += q * q;
  }
#pragma unroll
  for (int off = 32; off > 0; off >>= 1) {
    s += __shfl_xor(s, off, 64);
    ss += __shfl_xor(ss, off, 64);
  }
  float mu = s * (1.f / 384.f);
  float var = ss * (1.f / 384.f) - mu * mu;
  float rs = rsqrtf(var + 1e-5f);
  bf16* orow = out + (size_t)t * CDIM;
#pragma unroll
  for (int j = 0; j < 6; ++j) {
    int c = j * 64 + lane;
    orow[c] = f2bf((v[j] - mu) * rs * g[c] + b[c]);
  }
}

// ============ m97-style GEMM: 128x128 tile, BK=32, global_load_lds ==========
// A [M][K] bf16 row-major; Bt [N][K] bf16 row-major. 256 thr = 4 waves, each
// computes 64x64 (4x4 of 16x16x32 MFMA). Epilogue via padded LDS transpose.
// EPI: 0=QKV scatter, 1=proj(+reverse+shortcut->f32), 2=FC1(+GELU->bf16),
//      3=FC2(+residual->f32)
template <int K, int EPI>
__global__ __launch_bounds__(256) void k_gemm(const bf16* __restrict__ A,
                                              const bf16* __restrict__ Bt,
                                              const float* __restrict__ bias,
                                              const float* __restrict__ extra,
                                              void* __restrict__ outp) {
  __shared__ __attribute__((aligned(16))) bf16 As[128 * 32];
  __shared__ __attribute__((aligned(16))) bf16 Bs[128 * 32];
  __shared__ __attribute__((aligned(16))) float eps[4][16][68];

  const int tid = threadIdx.x;
  const int wv = tid >> 6, lane = tid & 63;
  const int mblk = blockIdx.x * 128, nblk = blockIdx.y * 128;

  // staging: chunk c = wv*2+i covers rows c*16..c*16+15 of the tile
  const int srow = lane >> 2;
  const int skoff = (lane & 3) * 8;
  const bf16* ga0 = A + (size_t)(mblk + wv * 32 + srow) * K + skoff;
  const bf16* ga1 = ga0 + (size_t)16 * K;
  const bf16* gb0 = Bt + (size_t)(nblk + wv * 32 + srow) * K + skoff;
  const bf16* gb1 = gb0 + (size_t)16 * K;
  const bf16* lA0 = As + (wv * 2) * 512;
  const bf16* lA1 = As + (wv * 2 + 1) * 512;
  const bf16* lB0 = Bs + (wv * 2) * 512;
  const bf16* lB1 = Bs + (wv * 2 + 1) * 512;

  const int wr = wv >> 1, wc = wv & 1;
  const int mr = lane & 15, q = lane >> 4;
  const bf16* fa = As + (wr * 64 + mr) * 32 + q * 8;
  const bf16* fb = Bs + (wc * 64 + mr) * 32 + q * 8;

  floatx4 acc[4][4];
#pragma unroll
  for (int i = 0; i < 4; ++i)
#pragma unroll
    for (int j = 0; j < 4; ++j) acc[i][j] = floatx4{0.f, 0.f, 0.f, 0.f};

  for (int k0 = 0; k0 < K; k0 += 32) {
    __syncthreads();
    gload16(ga0 + k0, lA0);
    gload16(ga1 + k0, lA1);
    gload16(gb0 + k0, lB0);
    gload16(gb1 + k0, lB1);
    __syncthreads();
    short8 a[4], b[4];
#pragma unroll
    for (int mt = 0; mt < 4; ++mt) a[mt] = *(const short8*)(fa + mt * 512);
#pragma unroll
    for (int nt = 0; nt < 4; ++nt) b[nt] = *(const short8*)(fb + nt * 512);
#pragma unroll
    for (int mt = 0; mt < 4; ++mt)
#pragma unroll
      for (int nt = 0; nt < 4; ++nt)
        acc[mt][nt] = __builtin_amdgcn_mfma_f32_16x16x32_bf16(a[mt], b[nt], acc[mt][nt], 0, 0, 0);
  }

  // ---------------- epilogue: per-wave LDS transpose (FULLY UNROLLED:
  // runtime-indexed acc[] would spill the accumulators to scratch) ----------
  const int rr = lane >> 2, c0 = (lane & 3) * 16;
#pragma unroll
  for (int mt = 0; mt < 4; ++mt) {
#pragma unroll
    for (int nt = 0; nt < 4; ++nt)
#pragma unroll
      for (int r = 0; r < 4; ++r)
        eps[wv][q * 4 + r][nt * 16 + mr] = acc[mt][nt][r];
    // wave-private region; same-wave LDS ops are in program order
    float v[16];
#pragma unroll
    for (int j = 0; j < 4; ++j) {
      float4 t = *(const float4*)&eps[wv][rr][c0 + j * 4];
      v[j * 4 + 0] = t.x; v[j * 4 + 1] = t.y; v[j * 4 + 2] = t.z; v[j * 4 + 3] = t.w;
    }
    const int grow = mblk + wr * 64 + mt * 16 + rr;
    const int gcol = nblk + wc * 64 + c0;

    if constexpr (EPI == 0) {
      int win = grow >> 6, ntok = grow & 63;
      int s = gcol / 384;
      int rem = gcol - s * 384;
      int h = rem >> 5, d0 = rem & 31;  // d0 in {0,16}
      bf16* op = (bf16*)outp + (((size_t)s * 512 + win) * 12 + h) * 2048 + ntok * 32 + d0;
      uint4 pk;
      float bv[16];
#pragma unroll
      for (int j = 0; j < 16; ++j) bv[j] = v[j] + bias[gcol + j];
      pk.x = pack2(bv[0], bv[1]); pk.y = pack2(bv[2], bv[3]);
      pk.z = pack2(bv[4], bv[5]); pk.w = pack2(bv[6], bv[7]);
      *(uint4*)op = pk;
      pk.x = pack2(bv[8], bv[9]); pk.y = pack2(bv[10], bv[11]);
      pk.z = pack2(bv[12], bv[13]); pk.w = pack2(bv[14], bv[15]);
      *(uint4*)(op + 8) = pk;
    } else if constexpr (EPI == 1) {
      int win = grow >> 6, ntok = grow & 63;
      int bimg = win >> 4, wi = win & 15;
      int hh = (((wi >> 2) << 3) + (ntok >> 3) + 4) & 31;
      int ww = (((wi & 3) << 3) + (ntok & 7) + 4) & 31;
      size_t t = (size_t)bimg * 1024 + hh * 32 + ww;
      float* op = (float*)outp + t * CDIM + gcol;
      const float* xr = extra + t * CDIM + gcol;
#pragma unroll
      for (int j = 0; j < 4; ++j) {
        float4 xv = *(const float4*)(xr + j * 4);
        float4 ov;
        ov.x = xv.x + v[j * 4 + 0] + bias[gcol + j * 4 + 0];
        ov.y = xv.y + v[j * 4 + 1] + bias[gcol + j * 4 + 1];
        ov.z = xv.z + v[j * 4 + 2] + bias[gcol + j * 4 + 2];
        ov.w = xv.w + v[j * 4 + 3] + bias[gcol + j * 4 + 3];
        *(float4*)(op + j * 4) = ov;
      }
    } else if constexpr (EPI == 2) {
      float gv[16];
#pragma unroll
      for (int j = 0; j < 16; ++j) {
        float z = v[j] + bias[gcol + j];
        float u = 0.7978845608028654f * (z + 0.044715f * z * z * z);
        gv[j] = z / (1.f + __expf(-2.f * u));
      }
      bf16* op = (bf16*)outp + (size_t)grow * HID + gcol;
      uint4 pk;
      pk.x = pack2(gv[0], gv[1]); pk.y = pack2(gv[2], gv[3]);
      pk.z = pack2(gv[4], gv[5]); pk.w = pack2(gv[6], gv[7]);
      *(uint4*)op = pk;
      pk.x = pack2(gv[8], gv[9]); pk.y = pack2(gv[10], gv[11]);
      pk.z = pack2(gv[12], gv[13]); pk.w = pack2(gv[14], gv[15]);
      *(uint4*)(op + 8) = pk;
    } else {
      float* op = (float*)outp + (size_t)grow * CDIM + gcol;
      const float* xr = extra + (size_t)grow * CDIM + gcol;
#pragma unroll
      for (int j = 0; j < 4; ++j) {
        float4 xv = *(const float4*)(xr + j * 4);
        float4 ov;
        ov.x = xv.x + v[j * 4 + 0] + bias[gcol + j * 4 + 0];
        ov.y = xv.y + v[j * 4 + 1] + bias[gcol + j * 4 + 1];
        ov.z = xv.z + v[j * 4 + 2] + bias[gcol + j * 4 + 2];
        ov.w = xv.w + v[j * 4 + 3] + bias[gcol + j * 4 + 3];
        *(float4*)(op + j * 4) = ov;
      }
    }
  }
}

// ---------------- attention: 1 wave per (window, head) ----------------------
__global__ __launch_bounds__(64) void k_attn(const bf16* __restrict__ qkv,
                                             const float* __restrict__ tblg,
                                             bf16* __restrict__ out) {
  __shared__ __attribute__((aligned(16))) float ks[64][32];
  __shared__ __attribute__((aligned(16))) float vs[64][32];
  __shared__ float tbl[2700];
  __shared__ int rids[64];
  int bid = blockIdx.x;
  int win = bid / 12, head = bid - win * 12;
  int lane = threadIdx.x;
  for (int i = lane; i < 2700; i += 64) tbl[i] = tblg[i];

  size_t base = ((size_t)win * 12 + head) * 2048 + lane * 32;
  const uint4* qp = (const uint4*)(qkv + base);
  const uint4* kp = (const uint4*)(qkv + (size_t)12582912 + base);
  const uint4* vp = (const uint4*)(qkv + (size_t)25165824 + base);

  float qreg[32];
#pragma unroll
  for (int i = 0; i < 4; ++i) { uint4 u = qp[i]; unpack8(u, qreg + i * 8); }
#pragma unroll
  for (int i = 0; i < 4; ++i) {
    uint4 u = kp[i]; float f[8]; unpack8(u, f);
#pragma unroll
    for (int j = 0; j < 8; ++j) ks[lane][i * 8 + j] = f[j];
  }
#pragma unroll
  for (int i = 0; i < 4; ++i) {
    uint4 u = vp[i]; float f[8]; unpack8(u, f);
#pragma unroll
    for (int j = 0; j < 8; ++j) vs[lane][i * 8 + j] = f[j];
  }
  int wi = win & 15;
  int hb = (wi >> 2) << 3, wb = (wi & 3) << 3;
  int r_i = lane >> 3, c_i = lane & 7;
  int rh = hb + r_i, rw = wb + c_i;
  int rid = (rh < 24 ? 0 : (rh < 28 ? 1 : 2)) * 3 + (rw < 24 ? 0 : (rw < 28 ? 1 : 2));
  rids[lane] = rid;
  __syncthreads();

  float s[64];
  float mx = -1e30f;
#pragma unroll
  for (int j = 0; j < 64; ++j) {
    const float4* kr = (const float4*)ks[j];
    float dot = 0.f;
#pragma unroll
    for (int d4 = 0; d4 < 8; ++d4) {
      float4 kk = kr[d4];
      dot += qreg[d4 * 4 + 0] * kk.x;
      dot += qreg[d4 * 4 + 1] * kk.y;
      dot += qreg[d4 * 4 + 2] * kk.z;
      dot += qreg[d4 * 4 + 3] * kk.w;
    }
    int r_j = j >> 3, c_j = j & 7;
    float bias = tbl[((r_i - r_j + 7) * 15 + (c_i - c_j + 7)) * 12 + head];
    float val = dot * 0.17677669529663687f + bias + (rid == rids[j] ? 0.f : -100.f);
    s[j] = val;
    mx = fmaxf(mx, val);
  }
  float l = 0.f;
#pragma unroll
  for (int j = 0; j < 64; ++j) {
    float p = __expf(s[j] - mx);
    s[j] = p;
    l += p;
  }
  float inv = 1.f / l;
  float o[32];
#pragma unroll
  for (int d = 0; d < 32; ++d) o[d] = 0.f;
#pragma unroll
  for (int j = 0; j < 64; ++j) {
    float p = s[j];
    const float4* vr = (const float4*)vs[j];
#pragma unroll
    for (int d4 = 0; d4 < 8; ++d4) {
      float4 vv = vr[d4];
      o[d4 * 4 + 0] += p * vv.x;
      o[d4 * 4 + 1] += p * vv.y;
      o[d4 * 4 + 2] += p * vv.z;
      o[d4 * 4 + 3] += p * vv.w;
    }
  }
  uint4* o4 = (uint4*)(out + ((size_t)win * 64 + lane) * CDIM + head * 32);
#pragma unroll
  for (int i = 0; i < 4; ++i) {
    uint4 pk;
    pk.x = pack2(o[i * 8 + 0] * inv, o[i * 8 + 1] * inv);
    pk.y = pack2(o[i * 8 + 2] * inv, o[i * 8 + 3] * inv);
    pk.z = pack2(o[i * 8 + 4] * inv, o[i * 8 + 5] * inv);
    pk.w = pack2(o[i * 8 + 6] * inv, o[i * 8 + 7] * inv);
    o4[i] = pk;
  }
}

extern "C" void kernel_launch(void* const* d_in, const int* in_sizes, int n_in,
                              void* d_out, int out_size, void* d_ws, size_t ws_size,
                              hipStream_t stream) {
  const float* x = (const float*)d_in[0];
  const float* n1g = (const float*)d_in[1];
  const float* n1b = (const float*)d_in[2];
  const float* qkv_w = (const float*)d_in[3];
  const float* qkv_b = (const float*)d_in[4];
  const float* reltbl = (const float*)d_in[5];
  const float* proj_w = (const float*)d_in[6];
  const float* proj_b = (const float*)d_in[7];
  const float* n2g = (const float*)d_in[8];
  const float* n2b = (const float*)d_in[9];
  const float* fc1_w = (const float*)d_in[10];
  const float* fc1_b = (const float*)d_in[11];
  const float* fc2_w = (const float*)d_in[12];
  const float* fc2_b = (const float*)d_in[13];
  float* out = (float*)d_out;

  char* p = (char*)d_ws;
  bf16* w_qkv_t = (bf16*)p;  p += (size_t)442368 * 2;
  bf16* w_proj_t = (bf16*)p; p += (size_t)147456 * 2;
  bf16* w_fc1_t = (bf16*)p;  p += (size_t)589824 * 2;
  bf16* w_fc2_t = (bf16*)p;  p += (size_t)589824 * 2;
  bf16* bufA = (bf16*)p;     p += (size_t)12582912 * 2;
  bf16* qkvb = (bf16*)p;     p += (size_t)37748736 * 2;
  bf16* attno = (bf16*)p;    p += (size_t)12582912 * 2;
  float* x1 = (float*)p;     p += (size_t)12582912 * 4;
  bf16* hidden = qkvb;  // [T][1536] bf16, reuses dead qkv/attn regions

  k_convt<<<dim3((442368 + 255) / 256), dim3(256), 0, stream>>>(qkv_w, w_qkv_t, 384, 1152);
  k_convt<<<dim3((147456 + 255) / 256), dim3(256), 0, stream>>>(proj_w, w_proj_t, 384, 384);
  k_convt<<<dim3((589824 + 255) / 256), dim3(256), 0, stream>>>(fc1_w, w_fc1_t, 384, 1536);
  k_convt<<<dim3((589824 + 255) / 256), dim3(256), 0, stream>>>(fc2_w, w_fc2_t, 1536, 384);

  k_ln1<<<dim3(8192), dim3(256), 0, stream>>>(x, n1g, n1b, bufA);
  k_gemm<384, 0><<<dim3(256, 9), dim3(256), 0, stream>>>(bufA, w_qkv_t, qkv_b, nullptr, qkvb);
  k_attn<<<dim3(6144), dim3(64), 0, stream>>>(qkvb, reltbl, attno);
  k_gemm<384, 1><<<dim3(256, 3), dim3(256), 0, stream>>>(attno, w_proj_t, proj_b, x, x1);
  k_ln2<<<dim3(8192), dim3(256), 0, stream>>>(x1, n2g, n2b, bufA);
  k_gemm<384, 2><<<dim3(256, 12), dim3(256), 0, stream>>>(bufA, w_fc1_t, fc1_b, nullptr, hidden);
  k_gemm<1536, 3><<<dim3(256, 3), dim3(256), 0, stream>>>(hidden, w_fc2_t, fc2_b, x1, out);
}

// Round 4
// 511.232 us; speedup vs baseline: 3.3640x; 1.1632x over previous
//
#include <hip/hip_runtime.h>
#include <hip/hip_bf16.h>
#include <math.h>

typedef __hip_bfloat16 bf16;
typedef __attribute__((ext_vector_type(8))) short short8;
typedef __attribute__((ext_vector_type(4))) float floatx4;

static constexpr int TOK = 32768;
static constexpr int CDIM = 384;
static constexpr int HID = 1536;

__device__ __forceinline__ bf16 f2bf(float v) { return __float2bfloat16(v); }

__device__ __forceinline__ void unpack8(uint4 u, float* f) {
  f[0] = __uint_as_float(u.x << 16); f[1] = __uint_as_float(u.x & 0xffff0000u);
  f[2] = __uint_as_float(u.y << 16); f[3] = __uint_as_float(u.y & 0xffff0000u);
  f[4] = __uint_as_float(u.z << 16); f[5] = __uint_as_float(u.z & 0xffff0000u);
  f[6] = __uint_as_float(u.w << 16); f[7] = __uint_as_float(u.w & 0xffff0000u);
}

__device__ __forceinline__ unsigned short bf_bits(float a) {
  bf16 h = __float2bfloat16(a);
  unsigned short u;
  __builtin_memcpy(&u, &h, 2);
  return u;
}
__device__ __forceinline__ unsigned pack2(float a, float b) {
  return (unsigned)bf_bits(a) | ((unsigned)bf_bits(b) << 16);
}

// async global -> LDS, 16 bytes per lane. LDS dest = wave-uniform base + lane*16.
typedef const __attribute__((address_space(1))) unsigned gas_t;
typedef __attribute__((address_space(3))) unsigned las_t;
__device__ __forceinline__ void gload16(const bf16* g, const bf16* l) {
  __builtin_amdgcn_global_load_lds((gas_t*)g, (las_t*)l, 16, 0, 0);
}

// ---------------- weight fp32 -> bf16 transposed ----------------
__global__ void k_convt(const float* __restrict__ src, bf16* __restrict__ dst,
                        int Kd, int Nd) {
  int tid = blockIdx.x * 256 + threadIdx.x;
  if (tid >= Kd * Nd) return;
  int k = tid / Nd, n = tid - k * Nd;
  dst[(size_t)n * Kd + k] = f2bf(src[tid]);
}

// ---------------- LN1 + shift + window partition (4 tokens/block) -----------
__global__ __launch_bounds__(256) void k_ln1(const float* __restrict__ x,
                                             const float* __restrict__ g,
                                             const float* __restrict__ b,
                                             bf16* __restrict__ out) {
  int wt = blockIdx.x * 4 + (threadIdx.x >> 6);
  int lane = threadIdx.x & 63;
  int win = wt >> 6, ntok = wt & 63;
  int bimg = win >> 4, wi = win & 15;
  int sh = (((wi >> 2) << 3) + (ntok >> 3) + 4) & 31;
  int sw = (((wi & 3) << 3) + (ntok & 7) + 4) & 31;
  const float* xr = x + ((size_t)bimg * 1024 + sh * 32 + sw) * CDIM;
  float v[6]; float s = 0.f, ss = 0.f;
#pragma unroll
  for (int j = 0; j < 6; ++j) {
    float t = xr[j * 64 + lane];
    v[j] = t; s += t; ss += t * t;
  }
#pragma unroll
  for (int off = 32; off > 0; off >>= 1) {
    s += __shfl_xor(s, off, 64);
    ss += __shfl_xor(ss, off, 64);
  }
  float mu = s * (1.f / 384.f);
  float var = ss * (1.f / 384.f) - mu * mu;
  float rs = rsqrtf(var + 1e-5f);
  bf16* orow = out + (size_t)wt * CDIM;
#pragma unroll
  for (int j = 0; j < 6; ++j) {
    int c = j * 64 + lane;
    orow[c] = f2bf((v[j] - mu) * rs * g[c] + b[c]);
  }
}

// ---------------- LN2 (normal token order, 4 tokens/block) ------------------
__global__ __launch_bounds__(256) void k_ln2(const float* __restrict__ x1,
                                             const float* __restrict__ g,
                                             const float* __restrict__ b,
                                             bf16* __restrict__ out) {
  int t = blockIdx.x * 4 + (threadIdx.x >> 6);
  int lane = threadIdx.x & 63;
  const float* xr = x1 + (size_t)t * CDIM;
  float v[6]; float s = 0.f, ss = 0.f;
#pragma unroll
  for (int j = 0; j < 6; ++j) {
    float q = xr[j * 64 + lane];
    v[j] = q; s += q; ss += q * q;
  }
#pragma unroll
  for (int off = 32; off > 0; off >>= 1) {
    s += __shfl_xor(s, off, 64);
    ss += __shfl_xor(ss, off, 64);
  }
  float mu = s * (1.f / 384.f);
  float var = ss * (1.f / 384.f) - mu * mu;
  float rs = rsqrtf(var + 1e-5f);
  bf16* orow = out + (size_t)t * CDIM;
#pragma unroll
  for (int j = 0; j < 6; ++j) {
    int c = j * 64 + lane;
    orow[c] = f2bf((v[j] - mu) * rs * g[c] + b[c]);
  }
}

// ============ m97-style GEMM: 128x128 tile, BK=32, global_load_lds ==========
// Grid: blockIdx.x = column tile (FAST-varying -> A-tile L2 reuse),
//       blockIdx.y = row tile.
// EPI: 0=QKV scatter, 1=proj(+reverse+shortcut->f32), 2=FC1(+GELU->bf16),
//      3=FC2(+residual->f32)
template <int K, int EPI>
__global__ __launch_bounds__(256) void k_gemm(const bf16* __restrict__ A,
                                              const bf16* __restrict__ Bt,
                                              const float* __restrict__ bias,
                                              const float* __restrict__ extra,
                                              void* __restrict__ outp) {
  __shared__ __attribute__((aligned(16))) bf16 As[128 * 32];
  __shared__ __attribute__((aligned(16))) bf16 Bs[128 * 32];
  __shared__ __attribute__((aligned(16))) float eps[4][16][68];

  const int tid = threadIdx.x;
  const int wv = tid >> 6, lane = tid & 63;
  const int mblk = blockIdx.y * 128, nblk = blockIdx.x * 128;

  const int srow = lane >> 2;
  const int skoff = (lane & 3) * 8;
  const bf16* ga0 = A + (size_t)(mblk + wv * 32 + srow) * K + skoff;
  const bf16* ga1 = ga0 + (size_t)16 * K;
  const bf16* gb0 = Bt + (size_t)(nblk + wv * 32 + srow) * K + skoff;
  const bf16* gb1 = gb0 + (size_t)16 * K;
  const bf16* lA0 = As + (wv * 2) * 512;
  const bf16* lA1 = As + (wv * 2 + 1) * 512;
  const bf16* lB0 = Bs + (wv * 2) * 512;
  const bf16* lB1 = Bs + (wv * 2 + 1) * 512;

  const int wr = wv >> 1, wc = wv & 1;
  const int mr = lane & 15, q = lane >> 4;
  const bf16* fa = As + (wr * 64 + mr) * 32 + q * 8;
  const bf16* fb = Bs + (wc * 64 + mr) * 32 + q * 8;

  floatx4 acc[4][4];
#pragma unroll
  for (int i = 0; i < 4; ++i)
#pragma unroll
    for (int j = 0; j < 4; ++j) acc[i][j] = floatx4{0.f, 0.f, 0.f, 0.f};

  for (int k0 = 0; k0 < K; k0 += 32) {
    __syncthreads();
    gload16(ga0 + k0, lA0);
    gload16(ga1 + k0, lA1);
    gload16(gb0 + k0, lB0);
    gload16(gb1 + k0, lB1);
    __syncthreads();
    short8 a[4], b[4];
#pragma unroll
    for (int mt = 0; mt < 4; ++mt) a[mt] = *(const short8*)(fa + mt * 512);
#pragma unroll
    for (int nt = 0; nt < 4; ++nt) b[nt] = *(const short8*)(fb + nt * 512);
#pragma unroll
    for (int mt = 0; mt < 4; ++mt)
#pragma unroll
      for (int nt = 0; nt < 4; ++nt)
        acc[mt][nt] = __builtin_amdgcn_mfma_f32_16x16x32_bf16(a[mt], b[nt], acc[mt][nt], 0, 0, 0);
  }

  // epilogue: per-wave LDS transpose (FULLY UNROLLED — runtime-indexed acc[]
  // would spill accumulators to scratch, the R2 2.07GB WRITE_SIZE disaster)
  const int rr = lane >> 2, c0 = (lane & 3) * 16;
#pragma unroll
  for (int mt = 0; mt < 4; ++mt) {
#pragma unroll
    for (int nt = 0; nt < 4; ++nt)
#pragma unroll
      for (int r = 0; r < 4; ++r)
        eps[wv][q * 4 + r][nt * 16 + mr] = acc[mt][nt][r];
    float v[16];
#pragma unroll
    for (int j = 0; j < 4; ++j) {
      float4 t = *(const float4*)&eps[wv][rr][c0 + j * 4];
      v[j * 4 + 0] = t.x; v[j * 4 + 1] = t.y; v[j * 4 + 2] = t.z; v[j * 4 + 3] = t.w;
    }
    const int grow = mblk + wr * 64 + mt * 16 + rr;
    const int gcol = nblk + wc * 64 + c0;

    if constexpr (EPI == 0) {
      int win = grow >> 6, ntok = grow & 63;
      int s = gcol / 384;
      int rem = gcol - s * 384;
      int h = rem >> 5, d0 = rem & 31;  // d0 in {0,16}
      bf16* op = (bf16*)outp + (((size_t)s * 512 + win) * 12 + h) * 2048 + ntok * 32 + d0;
      uint4 pk;
      float bv[16];
#pragma unroll
      for (int j = 0; j < 16; ++j) bv[j] = v[j] + bias[gcol + j];
      pk.x = pack2(bv[0], bv[1]); pk.y = pack2(bv[2], bv[3]);
      pk.z = pack2(bv[4], bv[5]); pk.w = pack2(bv[6], bv[7]);
      *(uint4*)op = pk;
      pk.x = pack2(bv[8], bv[9]); pk.y = pack2(bv[10], bv[11]);
      pk.z = pack2(bv[12], bv[13]); pk.w = pack2(bv[14], bv[15]);
      *(uint4*)(op + 8) = pk;
    } else if constexpr (EPI == 1) {
      int win = grow >> 6, ntok = grow & 63;
      int bimg = win >> 4, wi = win & 15;
      int hh = (((wi >> 2) << 3) + (ntok >> 3) + 4) & 31;
      int ww = (((wi & 3) << 3) + (ntok & 7) + 4) & 31;
      size_t t = (size_t)bimg * 1024 + hh * 32 + ww;
      float* op = (float*)outp + t * CDIM + gcol;
      const float* xr = extra + t * CDIM + gcol;
#pragma unroll
      for (int j = 0; j < 4; ++j) {
        float4 xv = *(const float4*)(xr + j * 4);
        float4 ov;
        ov.x = xv.x + v[j * 4 + 0] + bias[gcol + j * 4 + 0];
        ov.y = xv.y + v[j * 4 + 1] + bias[gcol + j * 4 + 1];
        ov.z = xv.z + v[j * 4 + 2] + bias[gcol + j * 4 + 2];
        ov.w = xv.w + v[j * 4 + 3] + bias[gcol + j * 4 + 3];
        *(float4*)(op + j * 4) = ov;
      }
    } else if constexpr (EPI == 2) {
      float gv[16];
#pragma unroll
      for (int j = 0; j < 16; ++j) {
        float z = v[j] + bias[gcol + j];
        float u = 0.7978845608028654f * (z + 0.044715f * z * z * z);
        gv[j] = z / (1.f + __expf(-2.f * u));
      }
      bf16* op = (bf16*)outp + (size_t)grow * HID + gcol;
      uint4 pk;
      pk.x = pack2(gv[0], gv[1]); pk.y = pack2(gv[2], gv[3]);
      pk.z = pack2(gv[4], gv[5]); pk.w = pack2(gv[6], gv[7]);
      *(uint4*)op = pk;
      pk.x = pack2(gv[8], gv[9]); pk.y = pack2(gv[10], gv[11]);
      pk.z = pack2(gv[12], gv[13]); pk.w = pack2(gv[14], gv[15]);
      *(uint4*)(op + 8) = pk;
    } else {
      float* op = (float*)outp + (size_t)grow * CDIM + gcol;
      const float* xr = extra + (size_t)grow * CDIM + gcol;
#pragma unroll
      for (int j = 0; j < 4; ++j) {
        float4 xv = *(const float4*)(xr + j * 4);
        float4 ov;
        ov.x = xv.x + v[j * 4 + 0] + bias[gcol + j * 4 + 0];
        ov.y = xv.y + v[j * 4 + 1] + bias[gcol + j * 4 + 1];
        ov.z = xv.z + v[j * 4 + 2] + bias[gcol + j * 4 + 2];
        ov.w = xv.w + v[j * 4 + 3] + bias[gcol + j * 4 + 3];
        *(float4*)(op + j * 4) = ov;
      }
    }
  }
}

// ---------------- attention: 1 wave per (window, head), fused single pass ---
// No max-subtraction: scores are O(1) (weights ~0.02 scale); masked entries
// get -100 -> exp underflows to exactly 0, matching the reference softmax.
__global__ __launch_bounds__(64) void k_attn(const bf16* __restrict__ qkv,
                                             const float* __restrict__ tblg,
                                             bf16* __restrict__ out) {
  // stride 36 floats: float4-aligned rows (36*4=144B) + bank spread
  __shared__ __attribute__((aligned(16))) float ks[64][36];
  __shared__ __attribute__((aligned(16))) float vs[64][36];
  __shared__ float tbl[228];
  int bid = blockIdx.x;
  int win = bid / 12, head = bid - win * 12;
  int lane = threadIdx.x;

  // per-head slice of the rel-bias table: 225 floats (vs 10.8KB full table)
  for (int i = lane; i < 225; i += 64) tbl[i] = tblg[i * 12 + head];

  size_t base = ((size_t)win * 12 + head) * 2048 + lane * 32;
  const uint4* qp = (const uint4*)(qkv + base);
  const uint4* kp = (const uint4*)(qkv + (size_t)12582912 + base);
  const uint4* vp = (const uint4*)(qkv + (size_t)25165824 + base);

  float qreg[32];
#pragma unroll
  for (int i = 0; i < 4; ++i) { uint4 u = qp[i]; unpack8(u, qreg + i * 8); }
#pragma unroll
  for (int i = 0; i < 4; ++i) {
    uint4 u = kp[i]; float f[8]; unpack8(u, f);
    *(float4*)&ks[lane][i * 8] = make_float4(f[0], f[1], f[2], f[3]);
    *(float4*)&ks[lane][i * 8 + 4] = make_float4(f[4], f[5], f[6], f[7]);
  }
#pragma unroll
  for (int i = 0; i < 4; ++i) {
    uint4 u = vp[i]; float f[8]; unpack8(u, f);
    *(float4*)&vs[lane][i * 8] = make_float4(f[0], f[1], f[2], f[3]);
    *(float4*)&vs[lane][i * 8 + 4] = make_float4(f[4], f[5], f[6], f[7]);
  }

  // region mask via ballot: bit j of `mask` = (rid_j == rid_lane)
  int wi = win & 15;
  int r_i = lane >> 3, c_i = lane & 7;
  int rh = ((wi >> 2) << 3) + r_i, rw = ((wi & 3) << 3) + c_i;
  int rid = (rh < 24 ? 0 : (rh < 28 ? 1 : 2)) * 3 + (rw < 24 ? 0 : (rw < 28 ? 1 : 2));
  unsigned long long mask = 0;
#pragma unroll
  for (int v = 0; v < 9; ++v) {
    unsigned long long bb = __ballot(rid == v);
    if (rid == v) mask = bb;
  }
  const int base_i = r_i * 15 + c_i;
  __syncthreads();

  float o[32];
#pragma unroll
  for (int d = 0; d < 32; ++d) o[d] = 0.f;
  float l = 0.f;
#pragma unroll 2
  for (int j = 0; j < 64; ++j) {
    const float4* kr = (const float4*)ks[j];
    float dot = 0.f;
#pragma unroll
    for (int d4 = 0; d4 < 8; ++d4) {
      float4 kk = kr[d4];
      dot += qreg[d4 * 4 + 0] * kk.x;
      dot += qreg[d4 * 4 + 1] * kk.y;
      dot += qreg[d4 * 4 + 2] * kk.z;
      dot += qreg[d4 * 4 + 3] * kk.w;
    }
    int off_j = 112 - (j >> 3) * 15 - (j & 7);
    float bias = tbl[base_i + off_j];
    float madd = ((mask >> j) & 1ull) ? 0.f : -100.f;
    float p = __expf(dot * 0.17677669529663687f + bias + madd);
    l += p;
    const float4* vr = (const float4*)vs[j];
#pragma unroll
    for (int d4 = 0; d4 < 8; ++d4) {
      float4 vv = vr[d4];
      o[d4 * 4 + 0] += p * vv.x;
      o[d4 * 4 + 1] += p * vv.y;
      o[d4 * 4 + 2] += p * vv.z;
      o[d4 * 4 + 3] += p * vv.w;
    }
  }
  float inv = 1.f / l;
  uint4* o4 = (uint4*)(out + ((size_t)win * 64 + lane) * CDIM + head * 32);
#pragma unroll
  for (int i = 0; i < 4; ++i) {
    uint4 pk;
    pk.x = pack2(o[i * 8 + 0] * inv, o[i * 8 + 1] * inv);
    pk.y = pack2(o[i * 8 + 2] * inv, o[i * 8 + 3] * inv);
    pk.z = pack2(o[i * 8 + 4] * inv, o[i * 8 + 5] * inv);
    pk.w = pack2(o[i * 8 + 6] * inv, o[i * 8 + 7] * inv);
    o4[i] = pk;
  }
}

extern "C" void kernel_launch(void* const* d_in, const int* in_sizes, int n_in,
                              void* d_out, int out_size, void* d_ws, size_t ws_size,
                              hipStream_t stream) {
  const float* x = (const float*)d_in[0];
  const float* n1g = (const float*)d_in[1];
  const float* n1b = (const float*)d_in[2];
  const float* qkv_w = (const float*)d_in[3];
  const float* qkv_b = (const float*)d_in[4];
  const float* reltbl = (const float*)d_in[5];
  const float* proj_w = (const float*)d_in[6];
  const float* proj_b = (const float*)d_in[7];
  const float* n2g = (const float*)d_in[8];
  const float* n2b = (const float*)d_in[9];
  const float* fc1_w = (const float*)d_in[10];
  const float* fc1_b = (const float*)d_in[11];
  const float* fc2_w = (const float*)d_in[12];
  const float* fc2_b = (const float*)d_in[13];
  float* out = (float*)d_out;

  char* p = (char*)d_ws;
  bf16* w_qkv_t = (bf16*)p;  p += (size_t)442368 * 2;
  bf16* w_proj_t = (bf16*)p; p += (size_t)147456 * 2;
  bf16* w_fc1_t = (bf16*)p;  p += (size_t)589824 * 2;
  bf16* w_fc2_t = (bf16*)p;  p += (size_t)589824 * 2;
  bf16* bufA = (bf16*)p;     p += (size_t)12582912 * 2;
  bf16* qkvb = (bf16*)p;     p += (size_t)37748736 * 2;
  bf16* attno = (bf16*)p;    p += (size_t)12582912 * 2;
  float* x1 = (float*)p;     p += (size_t)12582912 * 4;
  bf16* hidden = qkvb;  // [T][1536] bf16, reuses dead qkv/attn regions

  k_convt<<<dim3((442368 + 255) / 256), dim3(256), 0, stream>>>(qkv_w, w_qkv_t, 384, 1152);
  k_convt<<<dim3((147456 + 255) / 256), dim3(256), 0, stream>>>(proj_w, w_proj_t, 384, 384);
  k_convt<<<dim3((589824 + 255) / 256), dim3(256), 0, stream>>>(fc1_w, w_fc1_t, 384, 1536);
  k_convt<<<dim3((589824 + 255) / 256), dim3(256), 0, stream>>>(fc2_w, w_fc2_t, 1536, 384);

  k_ln1<<<dim3(8192), dim3(256), 0, stream>>>(x, n1g, n1b, bufA);
  // grids: x = column tiles (fast) so A row-tiles are reused in L2
  k_gemm<384, 0><<<dim3(9, 256), dim3(256), 0, stream>>>(bufA, w_qkv_t, qkv_b, nullptr, qkvb);
  k_attn<<<dim3(6144), dim3(64), 0, stream>>>(qkvb, reltbl, attno);
  k_gemm<384, 1><<<dim3(3, 256), dim3(256), 0, stream>>>(attno, w_proj_t, proj_b, x, x1);
  k_ln2<<<dim3(8192), dim3(256), 0, stream>>>(x1, n2g, n2b, bufA);
  k_gemm<384, 2><<<dim3(12, 256), dim3(256), 0, stream>>>(bufA, w_fc1_t, fc1_b, nullptr, hidden);
  k_gemm<1536, 3><<<dim3(3, 256), dim3(256), 0, stream>>>(hidden, w_fc2_t, fc2_b, x1, out);
}

// Round 5
// 448.886 us; speedup vs baseline: 3.8312x; 1.1389x over previous
//
#include <hip/hip_runtime.h>
#include <hip/hip_bf16.h>
#include <math.h>

typedef __hip_bfloat16 bf16;
typedef __attribute__((ext_vector_type(8))) short short8;
typedef __attribute__((ext_vector_type(4))) float floatx4;

static constexpr int TOK = 32768;
static constexpr int CDIM = 384;
static constexpr int HID = 1536;

__device__ __forceinline__ bf16 f2bf(float v) { return __float2bfloat16(v); }

__device__ __forceinline__ void unpack8(uint4 u, float* f) {
  f[0] = __uint_as_float(u.x << 16); f[1] = __uint_as_float(u.x & 0xffff0000u);
  f[2] = __uint_as_float(u.y << 16); f[3] = __uint_as_float(u.y & 0xffff0000u);
  f[4] = __uint_as_float(u.z << 16); f[5] = __uint_as_float(u.z & 0xffff0000u);
  f[6] = __uint_as_float(u.w << 16); f[7] = __uint_as_float(u.w & 0xffff0000u);
}

__device__ __forceinline__ unsigned short bf_bits(float a) {
  bf16 h = __float2bfloat16(a);
  unsigned short u;
  __builtin_memcpy(&u, &h, 2);
  return u;
}
__device__ __forceinline__ unsigned pack2(float a, float b) {
  return (unsigned)bf_bits(a) | ((unsigned)bf_bits(b) << 16);
}

typedef const __attribute__((address_space(1))) unsigned gas_t;
typedef __attribute__((address_space(3))) unsigned las_t;
__device__ __forceinline__ void gload16(const bf16* g, const bf16* l) {
  __builtin_amdgcn_global_load_lds((gas_t*)g, (las_t*)l, 16, 0, 0);
}

// ---------------- weight fp32 -> bf16 transposed ----------------
__global__ void k_convt(const float* __restrict__ src, bf16* __restrict__ dst,
                        int Kd, int Nd) {
  int tid = blockIdx.x * 256 + threadIdx.x;
  if (tid >= Kd * Nd) return;
  int k = tid / Nd, n = tid - k * Nd;
  dst[(size_t)n * Kd + k] = f2bf(src[tid]);
}

// ---------------- LN1 + shift + window partition (4 tokens/block) -----------
__global__ __launch_bounds__(256) void k_ln1(const float* __restrict__ x,
                                             const float* __restrict__ g,
                                             const float* __restrict__ b,
                                             bf16* __restrict__ out) {
  int wt = blockIdx.x * 4 + (threadIdx.x >> 6);
  int lane = threadIdx.x & 63;
  int win = wt >> 6, ntok = wt & 63;
  int bimg = win >> 4, wi = win & 15;
  int sh = (((wi >> 2) << 3) + (ntok >> 3) + 4) & 31;
  int sw = (((wi & 3) << 3) + (ntok & 7) + 4) & 31;
  const float* xr = x + ((size_t)bimg * 1024 + sh * 32 + sw) * CDIM;
  float v[6]; float s = 0.f, ss = 0.f;
#pragma unroll
  for (int j = 0; j < 6; ++j) {
    float t = xr[j * 64 + lane];
    v[j] = t; s += t; ss += t * t;
  }
#pragma unroll
  for (int off = 32; off > 0; off >>= 1) {
    s += __shfl_xor(s, off, 64);
    ss += __shfl_xor(ss, off, 64);
  }
  float mu = s * (1.f / 384.f);
  float var = ss * (1.f / 384.f) - mu * mu;
  float rs = rsqrtf(var + 1e-5f);
  bf16* orow = out + (size_t)wt * CDIM;
#pragma unroll
  for (int j = 0; j < 6; ++j) {
    int c = j * 64 + lane;
    orow[c] = f2bf((v[j] - mu) * rs * g[c] + b[c]);
  }
}

// ---------------- LN2 (normal token order, 4 tokens/block) ------------------
__global__ __launch_bounds__(256) void k_ln2(const float* __restrict__ x1,
                                             const float* __restrict__ g,
                                             const float* __restrict__ b,
                                             bf16* __restrict__ out) {
  int t = blockIdx.x * 4 + (threadIdx.x >> 6);
  int lane = threadIdx.x & 63;
  const float* xr = x1 + (size_t)t * CDIM;
  float v[6]; float s = 0.f, ss = 0.f;
#pragma unroll
  for (int j = 0; j < 6; ++j) {
    float q = xr[j * 64 + lane];
    v[j] = q; s += q; ss += q * q;
  }
#pragma unroll
  for (int off = 32; off > 0; off >>= 1) {
    s += __shfl_xor(s, off, 64);
    ss += __shfl_xor(ss, off, 64);
  }
  float mu = s * (1.f / 384.f);
  float var = ss * (1.f / 384.f) - mu * mu;
  float rs = rsqrtf(var + 1e-5f);
  bf16* orow = out + (size_t)t * CDIM;
#pragma unroll
  for (int j = 0; j < 6; ++j) {
    int c = j * 64 + lane;
    orow[c] = f2bf((v[j] - mu) * rs * g[c] + b[c]);
  }
}

// ============ GEMM: 128x128 tile, BK=64, XCD swizzle, LDS-aliased epilogue ==
// A [M][K] bf16 rm; Bt [N][K] bf16 rm. 256 thr = 4 waves, each 64x64.
// LDS k-block XOR swizzle (s8 = g8 ^ (row&7)): staging fetches per-lane
// swizzled global chunks (global side of global_load_lds is per-lane), so
// fragment ds_read_b128 at 128B row stride spreads across all 32 banks.
// 1D grid, flat%8 = XCD: each XCD owns RT/8 row tiles, col tiles innermost
// -> A row-tile fetched once per XCD L2.
template <int K, int EPI, int NT>
__global__ __launch_bounds__(256) void k_gemm(const bf16* __restrict__ A,
                                              const bf16* __restrict__ Bt,
                                              const float* __restrict__ bias,
                                              const float* __restrict__ extra,
                                              void* __restrict__ outp) {
  __shared__ __attribute__((aligned(16))) char pool[32768];
  bf16* As = (bf16*)pool;             // [128][64]
  bf16* Bs = (bf16*)(pool + 16384);   // [128][64]

  const int tid = threadIdx.x;
  const int wv = tid >> 6, lane = tid & 63;

  const int flat = blockIdx.x;
  const int xcd = flat & 7;
  const int idx = flat >> 3;
  const int rpx = (gridDim.x >> 3) / NT;  // row tiles per XCD
  const int cb = idx % NT;
  const int rb = idx / NT;
  const int mblk = (xcd * rpx + rb) * 128, nblk = cb * 128;

  // staging: wave wv stages rows [wv*32, wv*32+32) in 4 issues of 8 rows
  const int srow = lane >> 3;            // 0..7
  const int scol8 = (lane & 7) ^ srow;   // swizzled global k-block
  const bf16* gaw = A + (size_t)(mblk + wv * 32 + srow) * K + scol8 * 8;
  const bf16* gbw = Bt + (size_t)(nblk + wv * 32 + srow) * K + scol8 * 8;
  const bf16* lAw = As + wv * 2048;      // wave-uniform base; HW adds lane*16B
  const bf16* lBw = Bs + wv * 2048;

  const int wr = wv >> 1, wc = wv & 1;
  const int mr = lane & 15, q = lane >> 4;
  const bf16* faRow = As + (wr * 64 + mr) * 64;
  const bf16* fbRow = Bs + (wc * 64 + mr) * 64;
  const int sw0 = (q ^ (mr & 7)) * 8;        // kk=0  : g8 = q
  const int sw4 = ((q + 4) ^ (mr & 7)) * 8;  // kk=32 : g8 = q+4

  floatx4 acc[4][4];
#pragma unroll
  for (int i = 0; i < 4; ++i)
#pragma unroll
    for (int j = 0; j < 4; ++j) acc[i][j] = floatx4{0.f, 0.f, 0.f, 0.f};

  for (int k0 = 0; k0 < K; k0 += 64) {
    __syncthreads();
#pragma unroll
    for (int c = 0; c < 4; ++c) gload16(gaw + k0 + c * 8 * K, lAw + c * 512);
#pragma unroll
    for (int c = 0; c < 4; ++c) gload16(gbw + k0 + c * 8 * K, lBw + c * 512);
    __syncthreads();
    {
      short8 a[4], b[4];
#pragma unroll
      for (int mt = 0; mt < 4; ++mt) a[mt] = *(const short8*)(faRow + mt * 1024 + sw0);
#pragma unroll
      for (int nt = 0; nt < 4; ++nt) b[nt] = *(const short8*)(fbRow + nt * 1024 + sw0);
#pragma unroll
      for (int mt = 0; mt < 4; ++mt)
#pragma unroll
        for (int nt = 0; nt < 4; ++nt)
          acc[mt][nt] = __builtin_amdgcn_mfma_f32_16x16x32_bf16(a[mt], b[nt], acc[mt][nt], 0, 0, 0);
    }
    {
      short8 a[4], b[4];
#pragma unroll
      for (int mt = 0; mt < 4; ++mt) a[mt] = *(const short8*)(faRow + mt * 1024 + sw4);
#pragma unroll
      for (int nt = 0; nt < 4; ++nt) b[nt] = *(const short8*)(fbRow + nt * 1024 + sw4);
#pragma unroll
      for (int mt = 0; mt < 4; ++mt)
#pragma unroll
        for (int nt = 0; nt < 4; ++nt)
          acc[mt][nt] = __builtin_amdgcn_mfma_f32_16x16x32_bf16(a[mt], b[nt], acc[mt][nt], 0, 0, 0);
    }
  }

  // epilogue: staging LDS is dead -> alias per-wave transpose buffers onto it
  __syncthreads();
  float* epsw = (float*)pool + wv * (16 * 68);  // 4 x 4352B = 17408B < 32KB
  const int rr = lane >> 2, c0 = (lane & 3) * 16;
#pragma unroll
  for (int mt = 0; mt < 4; ++mt) {
#pragma unroll
    for (int nt = 0; nt < 4; ++nt)
#pragma unroll
      for (int r = 0; r < 4; ++r)
        epsw[(q * 4 + r) * 68 + nt * 16 + mr] = acc[mt][nt][r];
    float v[16];
#pragma unroll
    for (int j = 0; j < 4; ++j) {
      float4 t = *(const float4*)&epsw[rr * 68 + c0 + j * 4];
      v[j * 4 + 0] = t.x; v[j * 4 + 1] = t.y; v[j * 4 + 2] = t.z; v[j * 4 + 3] = t.w;
    }
    const int grow = mblk + wr * 64 + mt * 16 + rr;
    const int gcol = nblk + wc * 64 + c0;

    if constexpr (EPI == 0) {
      int win = grow >> 6, ntok = grow & 63;
      int s = gcol / 384;
      int rem = gcol - s * 384;
      int h = rem >> 5, d0 = rem & 31;
      bf16* op = (bf16*)outp + (((size_t)s * 512 + win) * 12 + h) * 2048 + ntok * 32 + d0;
      uint4 pk;
      float bv[16];
#pragma unroll
      for (int j = 0; j < 16; ++j) bv[j] = v[j] + bias[gcol + j];
      pk.x = pack2(bv[0], bv[1]); pk.y = pack2(bv[2], bv[3]);
      pk.z = pack2(bv[4], bv[5]); pk.w = pack2(bv[6], bv[7]);
      *(uint4*)op = pk;
      pk.x = pack2(bv[8], bv[9]); pk.y = pack2(bv[10], bv[11]);
      pk.z = pack2(bv[12], bv[13]); pk.w = pack2(bv[14], bv[15]);
      *(uint4*)(op + 8) = pk;
    } else if constexpr (EPI == 1) {
      int win = grow >> 6, ntok = grow & 63;
      int bimg = win >> 4, wi = win & 15;
      int hh = (((wi >> 2) << 3) + (ntok >> 3) + 4) & 31;
      int ww = (((wi & 3) << 3) + (ntok & 7) + 4) & 31;
      size_t t = (size_t)bimg * 1024 + hh * 32 + ww;
      float* op = (float*)outp + t * CDIM + gcol;
      const float* xr = extra + t * CDIM + gcol;
#pragma unroll
      for (int j = 0; j < 4; ++j) {
        float4 xv = *(const float4*)(xr + j * 4);
        float4 ov;
        ov.x = xv.x + v[j * 4 + 0] + bias[gcol + j * 4 + 0];
        ov.y = xv.y + v[j * 4 + 1] + bias[gcol + j * 4 + 1];
        ov.z = xv.z + v[j * 4 + 2] + bias[gcol + j * 4 + 2];
        ov.w = xv.w + v[j * 4 + 3] + bias[gcol + j * 4 + 3];
        *(float4*)(op + j * 4) = ov;
      }
    } else if constexpr (EPI == 2) {
      float gv[16];
#pragma unroll
      for (int j = 0; j < 16; ++j) {
        float z = v[j] + bias[gcol + j];
        float u = 0.7978845608028654f * (z + 0.044715f * z * z * z);
        gv[j] = z / (1.f + __expf(-2.f * u));
      }
      bf16* op = (bf16*)outp + (size_t)grow * HID + gcol;
      uint4 pk;
      pk.x = pack2(gv[0], gv[1]); pk.y = pack2(gv[2], gv[3]);
      pk.z = pack2(gv[4], gv[5]); pk.w = pack2(gv[6], gv[7]);
      *(uint4*)op = pk;
      pk.x = pack2(gv[8], gv[9]); pk.y = pack2(gv[10], gv[11]);
      pk.z = pack2(gv[12], gv[13]); pk.w = pack2(gv[14], gv[15]);
      *(uint4*)(op + 8) = pk;
    } else {
      float* op = (float*)outp + (size_t)grow * CDIM + gcol;
      const float* xr = extra + (size_t)grow * CDIM + gcol;
#pragma unroll
      for (int j = 0; j < 4; ++j) {
        float4 xv = *(const float4*)(xr + j * 4);
        float4 ov;
        ov.x = xv.x + v[j * 4 + 0] + bias[gcol + j * 4 + 0];
        ov.y = xv.y + v[j * 4 + 1] + bias[gcol + j * 4 + 1];
        ov.z = xv.z + v[j * 4 + 2] + bias[gcol + j * 4 + 2];
        ov.w = xv.w + v[j * 4 + 3] + bias[gcol + j * 4 + 3];
        *(float4*)(op + j * 4) = ov;
      }
    }
  }
}

// ---------------- attention: 1 wave per (window, head), fused single pass ---
__global__ __launch_bounds__(64) void k_attn(const bf16* __restrict__ qkv,
                                             const float* __restrict__ tblg,
                                             bf16* __restrict__ out) {
  __shared__ __attribute__((aligned(16))) float ks[64][36];
  __shared__ __attribute__((aligned(16))) float vs[64][36];
  __shared__ float tbl[228];
  int bid = blockIdx.x;
  int win = bid / 12, head = bid - win * 12;
  int lane = threadIdx.x;

  for (int i = lane; i < 225; i += 64) tbl[i] = tblg[i * 12 + head];

  size_t base = ((size_t)win * 12 + head) * 2048 + lane * 32;
  const uint4* qp = (const uint4*)(qkv + base);
  const uint4* kp = (const uint4*)(qkv + (size_t)12582912 + base);
  const uint4* vp = (const uint4*)(qkv + (size_t)25165824 + base);

  float qreg[32];
#pragma unroll
  for (int i = 0; i < 4; ++i) { uint4 u = qp[i]; unpack8(u, qreg + i * 8); }
#pragma unroll
  for (int i = 0; i < 4; ++i) {
    uint4 u = kp[i]; float f[8]; unpack8(u, f);
    *(float4*)&ks[lane][i * 8] = make_float4(f[0], f[1], f[2], f[3]);
    *(float4*)&ks[lane][i * 8 + 4] = make_float4(f[4], f[5], f[6], f[7]);
  }
#pragma unroll
  for (int i = 0; i < 4; ++i) {
    uint4 u = vp[i]; float f[8]; unpack8(u, f);
    *(float4*)&vs[lane][i * 8] = make_float4(f[0], f[1], f[2], f[3]);
    *(float4*)&vs[lane][i * 8 + 4] = make_float4(f[4], f[5], f[6], f[7]);
  }

  int wi = win & 15;
  int r_i = lane >> 3, c_i = lane & 7;
  int rh = ((wi >> 2) << 3) + r_i, rw = ((wi & 3) << 3) + c_i;
  int rid = (rh < 24 ? 0 : (rh < 28 ? 1 : 2)) * 3 + (rw < 24 ? 0 : (rw < 28 ? 1 : 2));
  unsigned long long mask = 0;
#pragma unroll
  for (int v = 0; v < 9; ++v) {
    unsigned long long bb = __ballot(rid == v);
    if (rid == v) mask = bb;
  }
  const int base_i = r_i * 15 + c_i;
  __syncthreads();

  float o[32];
#pragma unroll
  for (int d = 0; d < 32; ++d) o[d] = 0.f;
  float l = 0.f;
#pragma unroll 2
  for (int j = 0; j < 64; ++j) {
    const float4* kr = (const float4*)ks[j];
    float dot = 0.f;
#pragma unroll
    for (int d4 = 0; d4 < 8; ++d4) {
      float4 kk = kr[d4];
      dot += qreg[d4 * 4 + 0] * kk.x;
      dot += qreg[d4 * 4 + 1] * kk.y;
      dot += qreg[d4 * 4 + 2] * kk.z;
      dot += qreg[d4 * 4 + 3] * kk.w;
    }
    int off_j = 112 - (j >> 3) * 15 - (j & 7);
    float bias = tbl[base_i + off_j];
    float madd = ((mask >> j) & 1ull) ? 0.f : -100.f;
    float p = __expf(dot * 0.17677669529663687f + bias + madd);
    l += p;
    const float4* vr = (const float4*)vs[j];
#pragma unroll
    for (int d4 = 0; d4 < 8; ++d4) {
      float4 vv = vr[d4];
      o[d4 * 4 + 0] += p * vv.x;
      o[d4 * 4 + 1] += p * vv.y;
      o[d4 * 4 + 2] += p * vv.z;
      o[d4 * 4 + 3] += p * vv.w;
    }
  }
  float inv = 1.f / l;
  uint4* o4 = (uint4*)(out + ((size_t)win * 64 + lane) * CDIM + head * 32);
#pragma unroll
  for (int i = 0; i < 4; ++i) {
    uint4 pk;
    pk.x = pack2(o[i * 8 + 0] * inv, o[i * 8 + 1] * inv);
    pk.y = pack2(o[i * 8 + 2] * inv, o[i * 8 + 3] * inv);
    pk.z = pack2(o[i * 8 + 4] * inv, o[i * 8 + 5] * inv);
    pk.w = pack2(o[i * 8 + 6] * inv, o[i * 8 + 7] * inv);
    o4[i] = pk;
  }
}

extern "C" void kernel_launch(void* const* d_in, const int* in_sizes, int n_in,
                              void* d_out, int out_size, void* d_ws, size_t ws_size,
                              hipStream_t stream) {
  const float* x = (const float*)d_in[0];
  const float* n1g = (const float*)d_in[1];
  const float* n1b = (const float*)d_in[2];
  const float* qkv_w = (const float*)d_in[3];
  const float* qkv_b = (const float*)d_in[4];
  const float* reltbl = (const float*)d_in[5];
  const float* proj_w = (const float*)d_in[6];
  const float* proj_b = (const float*)d_in[7];
  const float* n2g = (const float*)d_in[8];
  const float* n2b = (const float*)d_in[9];
  const float* fc1_w = (const float*)d_in[10];
  const float* fc1_b = (const float*)d_in[11];
  const float* fc2_w = (const float*)d_in[12];
  const float* fc2_b = (const float*)d_in[13];
  float* out = (float*)d_out;

  char* p = (char*)d_ws;
  bf16* w_qkv_t = (bf16*)p;  p += (size_t)442368 * 2;
  bf16* w_proj_t = (bf16*)p; p += (size_t)147456 * 2;
  bf16* w_fc1_t = (bf16*)p;  p += (size_t)589824 * 2;
  bf16* w_fc2_t = (bf16*)p;  p += (size_t)589824 * 2;
  bf16* bufA = (bf16*)p;     p += (size_t)12582912 * 2;
  bf16* qkvb = (bf16*)p;     p += (size_t)37748736 * 2;
  bf16* attno = (bf16*)p;    p += (size_t)12582912 * 2;
  float* x1 = (float*)p;     p += (size_t)12582912 * 4;
  bf16* hidden = qkvb;  // reuses dead qkv/attn regions

  k_convt<<<dim3((442368 + 255) / 256), dim3(256), 0, stream>>>(qkv_w, w_qkv_t, 384, 1152);
  k_convt<<<dim3((147456 + 255) / 256), dim3(256), 0, stream>>>(proj_w, w_proj_t, 384, 384);
  k_convt<<<dim3((589824 + 255) / 256), dim3(256), 0, stream>>>(fc1_w, w_fc1_t, 384, 1536);
  k_convt<<<dim3((589824 + 255) / 256), dim3(256), 0, stream>>>(fc2_w, w_fc2_t, 1536, 384);

  k_ln1<<<dim3(8192), dim3(256), 0, stream>>>(x, n1g, n1b, bufA);
  k_gemm<384, 0, 9><<<dim3(9 * 256), dim3(256), 0, stream>>>(bufA, w_qkv_t, qkv_b, nullptr, qkvb);
  k_attn<<<dim3(6144), dim3(64), 0, stream>>>(qkvb, reltbl, attno);
  k_gemm<384, 1, 3><<<dim3(3 * 256), dim3(256), 0, stream>>>(attno, w_proj_t, proj_b, x, x1);
  k_ln2<<<dim3(8192), dim3(256), 0, stream>>>(x1, n2g, n2b, bufA);
  k_gemm<384, 2, 12><<<dim3(12 * 256), dim3(256), 0, stream>>>(bufA, w_fc1_t, fc1_b, nullptr, hidden);
  k_gemm<1536, 3, 3><<<dim3(3 * 256), dim3(256), 0, stream>>>(hidden, w_fc2_t, fc2_b, x1, out);
}

// Round 6
// 435.767 us; speedup vs baseline: 3.9466x; 1.0301x over previous
//
#include <hip/hip_runtime.h>
#include <hip/hip_bf16.h>
#include <math.h>

typedef __hip_bfloat16 bf16;
typedef __attribute__((ext_vector_type(8))) short short8;
typedef __attribute__((ext_vector_type(4))) float floatx4;

static constexpr int TOK = 32768;
static constexpr int CDIM = 384;
static constexpr int HID = 1536;

__device__ __forceinline__ bf16 f2bf(float v) { return __float2bfloat16(v); }

__device__ __forceinline__ unsigned short bf_bits(float a) {
  bf16 h = __float2bfloat16(a);
  unsigned short u;
  __builtin_memcpy(&u, &h, 2);
  return u;
}
__device__ __forceinline__ unsigned pack2(float a, float b) {
  return (unsigned)bf_bits(a) | ((unsigned)bf_bits(b) << 16);
}

typedef const __attribute__((address_space(1))) unsigned gas_t;
typedef __attribute__((address_space(3))) unsigned las_t;
__device__ __forceinline__ void gload16(const bf16* g, const bf16* l) {
  __builtin_amdgcn_global_load_lds((gas_t*)g, (las_t*)l, 16, 0, 0);
}

// ---------------- weight fp32 -> bf16 transposed ----------------
__global__ void k_convt(const float* __restrict__ src, bf16* __restrict__ dst,
                        int Kd, int Nd) {
  int tid = blockIdx.x * 256 + threadIdx.x;
  if (tid >= Kd * Nd) return;
  int k = tid / Nd, n = tid - k * Nd;
  dst[(size_t)n * Kd + k] = f2bf(src[tid]);
}

// ---------------- LN1 + shift + window partition (4 tokens/block) -----------
__global__ __launch_bounds__(256) void k_ln1(const float* __restrict__ x,
                                             const float* __restrict__ g,
                                             const float* __restrict__ b,
                                             bf16* __restrict__ out) {
  int wt = blockIdx.x * 4 + (threadIdx.x >> 6);
  int lane = threadIdx.x & 63;
  int win = wt >> 6, ntok = wt & 63;
  int bimg = win >> 4, wi = win & 15;
  int sh = (((wi >> 2) << 3) + (ntok >> 3) + 4) & 31;
  int sw = (((wi & 3) << 3) + (ntok & 7) + 4) & 31;
  const float* xr = x + ((size_t)bimg * 1024 + sh * 32 + sw) * CDIM;
  float v[6]; float s = 0.f, ss = 0.f;
#pragma unroll
  for (int j = 0; j < 6; ++j) {
    float t = xr[j * 64 + lane];
    v[j] = t; s += t; ss += t * t;
  }
#pragma unroll
  for (int off = 32; off > 0; off >>= 1) {
    s += __shfl_xor(s, off, 64);
    ss += __shfl_xor(ss, off, 64);
  }
  float mu = s * (1.f / 384.f);
  float var = ss * (1.f / 384.f) - mu * mu;
  float rs = rsqrtf(var + 1e-5f);
  bf16* orow = out + (size_t)wt * CDIM;
#pragma unroll
  for (int j = 0; j < 6; ++j) {
    int c = j * 64 + lane;
    orow[c] = f2bf((v[j] - mu) * rs * g[c] + b[c]);
  }
}

// ---------------- LN2 (normal token order, 4 tokens/block) ------------------
__global__ __launch_bounds__(256) void k_ln2(const float* __restrict__ x1,
                                             const float* __restrict__ g,
                                             const float* __restrict__ b,
                                             bf16* __restrict__ out) {
  int t = blockIdx.x * 4 + (threadIdx.x >> 6);
  int lane = threadIdx.x & 63;
  const float* xr = x1 + (size_t)t * CDIM;
  float v[6]; float s = 0.f, ss = 0.f;
#pragma unroll
  for (int j = 0; j < 6; ++j) {
    float q = xr[j * 64 + lane];
    v[j] = q; s += q; ss += q * q;
  }
#pragma unroll
  for (int off = 32; off > 0; off >>= 1) {
    s += __shfl_xor(s, off, 64);
    ss += __shfl_xor(ss, off, 64);
  }
  float mu = s * (1.f / 384.f);
  float var = ss * (1.f / 384.f) - mu * mu;
  float rs = rsqrtf(var + 1e-5f);
  bf16* orow = out + (size_t)t * CDIM;
#pragma unroll
  for (int j = 0; j < 6; ++j) {
    int c = j * 64 + lane;
    orow[c] = f2bf((v[j] - mu) * rs * g[c] + b[c]);
  }
}

// ============ GEMM: 128x128 tile, BK=64, XCD swizzle, LDS-aliased epilogue ==
template <int K, int EPI, int NT>
__global__ __launch_bounds__(256) void k_gemm(const bf16* __restrict__ A,
                                              const bf16* __restrict__ Bt,
                                              const float* __restrict__ bias,
                                              const float* __restrict__ extra,
                                              void* __restrict__ outp) {
  __shared__ __attribute__((aligned(16))) char pool[32768];
  bf16* As = (bf16*)pool;             // [128][64]
  bf16* Bs = (bf16*)(pool + 16384);   // [128][64]

  const int tid = threadIdx.x;
  const int wv = tid >> 6, lane = tid & 63;

  const int flat = blockIdx.x;
  const int xcd = flat & 7;
  const int idx = flat >> 3;
  const int rpx = (gridDim.x >> 3) / NT;
  const int cb = idx % NT;
  const int rb = idx / NT;
  const int mblk = (xcd * rpx + rb) * 128, nblk = cb * 128;

  const int srow = lane >> 3;
  const int scol8 = (lane & 7) ^ srow;
  const bf16* gaw = A + (size_t)(mblk + wv * 32 + srow) * K + scol8 * 8;
  const bf16* gbw = Bt + (size_t)(nblk + wv * 32 + srow) * K + scol8 * 8;
  const bf16* lAw = As + wv * 2048;
  const bf16* lBw = Bs + wv * 2048;

  const int wr = wv >> 1, wc = wv & 1;
  const int mr = lane & 15, q = lane >> 4;
  const bf16* faRow = As + (wr * 64 + mr) * 64;
  const bf16* fbRow = Bs + (wc * 64 + mr) * 64;
  const int sw0 = (q ^ (mr & 7)) * 8;
  const int sw4 = ((q + 4) ^ (mr & 7)) * 8;

  floatx4 acc[4][4];
#pragma unroll
  for (int i = 0; i < 4; ++i)
#pragma unroll
    for (int j = 0; j < 4; ++j) acc[i][j] = floatx4{0.f, 0.f, 0.f, 0.f};

  for (int k0 = 0; k0 < K; k0 += 64) {
    __syncthreads();
#pragma unroll
    for (int c = 0; c < 4; ++c) gload16(gaw + k0 + c * 8 * K, lAw + c * 512);
#pragma unroll
    for (int c = 0; c < 4; ++c) gload16(gbw + k0 + c * 8 * K, lBw + c * 512);
    __syncthreads();
    {
      short8 a[4], b[4];
#pragma unroll
      for (int mt = 0; mt < 4; ++mt) a[mt] = *(const short8*)(faRow + mt * 1024 + sw0);
#pragma unroll
      for (int nt = 0; nt < 4; ++nt) b[nt] = *(const short8*)(fbRow + nt * 1024 + sw0);
#pragma unroll
      for (int mt = 0; mt < 4; ++mt)
#pragma unroll
        for (int nt = 0; nt < 4; ++nt)
          acc[mt][nt] = __builtin_amdgcn_mfma_f32_16x16x32_bf16(a[mt], b[nt], acc[mt][nt], 0, 0, 0);
    }
    {
      short8 a[4], b[4];
#pragma unroll
      for (int mt = 0; mt < 4; ++mt) a[mt] = *(const short8*)(faRow + mt * 1024 + sw4);
#pragma unroll
      for (int nt = 0; nt < 4; ++nt) b[nt] = *(const short8*)(fbRow + nt * 1024 + sw4);
#pragma unroll
      for (int mt = 0; mt < 4; ++mt)
#pragma unroll
        for (int nt = 0; nt < 4; ++nt)
          acc[mt][nt] = __builtin_amdgcn_mfma_f32_16x16x32_bf16(a[mt], b[nt], acc[mt][nt], 0, 0, 0);
    }
  }

  __syncthreads();
  float* epsw = (float*)pool + wv * (16 * 68);
  const int rr = lane >> 2, c0 = (lane & 3) * 16;
#pragma unroll
  for (int mt = 0; mt < 4; ++mt) {
#pragma unroll
    for (int nt = 0; nt < 4; ++nt)
#pragma unroll
      for (int r = 0; r < 4; ++r)
        epsw[(q * 4 + r) * 68 + nt * 16 + mr] = acc[mt][nt][r];
    float v[16];
#pragma unroll
    for (int j = 0; j < 4; ++j) {
      float4 t = *(const float4*)&epsw[rr * 68 + c0 + j * 4];
      v[j * 4 + 0] = t.x; v[j * 4 + 1] = t.y; v[j * 4 + 2] = t.z; v[j * 4 + 3] = t.w;
    }
    const int grow = mblk + wr * 64 + mt * 16 + rr;
    const int gcol = nblk + wc * 64 + c0;

    if constexpr (EPI == 0) {
      int win = grow >> 6, ntok = grow & 63;
      int s = gcol / 384;
      int rem = gcol - s * 384;
      int h = rem >> 5, d0 = rem & 31;
      bf16* op = (bf16*)outp + (((size_t)s * 512 + win) * 12 + h) * 2048 + ntok * 32 + d0;
      uint4 pk;
      float bv[16];
#pragma unroll
      for (int j = 0; j < 16; ++j) bv[j] = v[j] + bias[gcol + j];
      pk.x = pack2(bv[0], bv[1]); pk.y = pack2(bv[2], bv[3]);
      pk.z = pack2(bv[4], bv[5]); pk.w = pack2(bv[6], bv[7]);
      *(uint4*)op = pk;
      pk.x = pack2(bv[8], bv[9]); pk.y = pack2(bv[10], bv[11]);
      pk.z = pack2(bv[12], bv[13]); pk.w = pack2(bv[14], bv[15]);
      *(uint4*)(op + 8) = pk;
    } else if constexpr (EPI == 1) {
      int win = grow >> 6, ntok = grow & 63;
      int bimg = win >> 4, wi = win & 15;
      int hh = (((wi >> 2) << 3) + (ntok >> 3) + 4) & 31;
      int ww = (((wi & 3) << 3) + (ntok & 7) + 4) & 31;
      size_t t = (size_t)bimg * 1024 + hh * 32 + ww;
      float* op = (float*)outp + t * CDIM + gcol;
      const float* xr = extra + t * CDIM + gcol;
#pragma unroll
      for (int j = 0; j < 4; ++j) {
        float4 xv = *(const float4*)(xr + j * 4);
        float4 ov;
        ov.x = xv.x + v[j * 4 + 0] + bias[gcol + j * 4 + 0];
        ov.y = xv.y + v[j * 4 + 1] + bias[gcol + j * 4 + 1];
        ov.z = xv.z + v[j * 4 + 2] + bias[gcol + j * 4 + 2];
        ov.w = xv.w + v[j * 4 + 3] + bias[gcol + j * 4 + 3];
        *(float4*)(op + j * 4) = ov;
      }
    } else if constexpr (EPI == 2) {
      float gv[16];
#pragma unroll
      for (int j = 0; j < 16; ++j) {
        float z = v[j] + bias[gcol + j];
        float u = 0.7978845608028654f * (z + 0.044715f * z * z * z);
        gv[j] = z / (1.f + __expf(-2.f * u));
      }
      bf16* op = (bf16*)outp + (size_t)grow * HID + gcol;
      uint4 pk;
      pk.x = pack2(gv[0], gv[1]); pk.y = pack2(gv[2], gv[3]);
      pk.z = pack2(gv[4], gv[5]); pk.w = pack2(gv[6], gv[7]);
      *(uint4*)op = pk;
      pk.x = pack2(gv[8], gv[9]); pk.y = pack2(gv[10], gv[11]);
      pk.z = pack2(gv[12], gv[13]); pk.w = pack2(gv[14], gv[15]);
      *(uint4*)(op + 8) = pk;
    } else {
      float* op = (float*)outp + (size_t)grow * CDIM + gcol;
      const float* xr = extra + (size_t)grow * CDIM + gcol;
#pragma unroll
      for (int j = 0; j < 4; ++j) {
        float4 xv = *(const float4*)(xr + j * 4);
        float4 ov;
        ov.x = xv.x + v[j * 4 + 0] + bias[gcol + j * 4 + 0];
        ov.y = xv.y + v[j * 4 + 1] + bias[gcol + j * 4 + 1];
        ov.z = xv.z + v[j * 4 + 2] + bias[gcol + j * 4 + 2];
        ov.w = xv.w + v[j * 4 + 3] + bias[gcol + j * 4 + 3];
        *(float4*)(op + j * 4) = ov;
      }
    }
  }
}

// ============ attention on MFMA: 1 wave per (window, head) ==================
// S = Q.K^T (16 MFMA, K-dim=32), epilogue in C-layout (scale+bias+mask+exp,
// row-sums via shfl), P -> LDS bf16 (A-layout round trip), O = P.V (16 MFMA,
// V pre-transposed in LDS), normalize, LDS round-trip -> 16B global stores.
// LDS pool aliases: Q[64][40]|K[64][40] -> P[64][72] -> Os[64][40]f32.
__global__ __launch_bounds__(64) void k_attn(const bf16* __restrict__ qkv,
                                             const float* __restrict__ tblg,
                                             bf16* __restrict__ out) {
  __shared__ __attribute__((aligned(16))) char pool[16384];
  bf16* Qs = (bf16*)pool;                                   // [64][40]
  bf16* Ks = (bf16*)(pool + 5120);                          // [64][40]
  bf16* Ps = (bf16*)pool;                                   // [64][72] alias
  float* Os = (float*)pool;                                 // [64][40] alias
  bf16* Vt = (bf16*)(pool + 10240);                         // [32][72]
  unsigned long long* msk = (unsigned long long*)(pool + 14848);  // [64]
  float* tbl = (float*)(pool + 15360);                      // [225]

  const int bid = blockIdx.x;
  const int win = bid / 12, head = bid - win * 12;
  const int lane = threadIdx.x;
  const int q = lane >> 4, mr = lane & 15;

  for (int i = lane; i < 225; i += 64) tbl[i] = tblg[i * 12 + head];

  size_t base = ((size_t)win * 12 + head) * 2048 + lane * 32;
  const uint4* qp = (const uint4*)(qkv + base);
  const uint4* kp = (const uint4*)(qkv + (size_t)12582912 + base);
  const uint4* vp = (const uint4*)(qkv + (size_t)25165824 + base);
#pragma unroll
  for (int i = 0; i < 4; ++i) *(uint4*)(Qs + lane * 40 + i * 8) = qp[i];
#pragma unroll
  for (int i = 0; i < 4; ++i) *(uint4*)(Ks + lane * 40 + i * 8) = kp[i];
  {
    union { uint4 u[4]; unsigned short h[32]; } vv;
#pragma unroll
    for (int i = 0; i < 4; ++i) vv.u[i] = vp[i];
    unsigned short* VtU = (unsigned short*)Vt;
#pragma unroll
    for (int d = 0; d < 32; ++d) VtU[d * 72 + lane] = vv.h[d];
  }
  {
    int wi = win & 15;
    int ri = lane >> 3, ci = lane & 7;
    int rh = ((wi >> 2) << 3) + ri, rw = ((wi & 3) << 3) + ci;
    int rid = (rh < 24 ? 0 : (rh < 28 ? 1 : 2)) * 3 + (rw < 24 ? 0 : (rw < 28 ? 1 : 2));
    unsigned long long m = 0;
#pragma unroll
    for (int v = 0; v < 9; ++v) {
      unsigned long long bb = __ballot(rid == v);
      if (rid == v) m = bb;
    }
    msk[lane] = m;
  }
  // single wave: LDS ops execute in program order, no barrier needed

  // ---- S = Q.K^T ----
  floatx4 sac[4][4];
#pragma unroll
  for (int i = 0; i < 4; ++i)
#pragma unroll
    for (int j = 0; j < 4; ++j) sac[i][j] = floatx4{0.f, 0.f, 0.f, 0.f};
  {
    short8 af[4], bf[4];
#pragma unroll
    for (int t = 0; t < 4; ++t) af[t] = *(const short8*)(Qs + (t * 16 + mr) * 40 + q * 8);
#pragma unroll
    for (int t = 0; t < 4; ++t) bf[t] = *(const short8*)(Ks + (t * 16 + mr) * 40 + q * 8);
#pragma unroll
    for (int mt = 0; mt < 4; ++mt)
#pragma unroll
      for (int nt = 0; nt < 4; ++nt)
        sac[mt][nt] = __builtin_amdgcn_mfma_f32_16x16x32_bf16(af[mt], bf[nt], sac[mt][nt], 0, 0, 0);
  }

  // ---- epilogue: scale + bias + mask + exp; row sums; P -> LDS bf16 ----
  float psum[4][4];
#pragma unroll
  for (int mt = 0; mt < 4; ++mt)
#pragma unroll
    for (int r = 0; r < 4; ++r) psum[mt][r] = 0.f;
#pragma unroll
  for (int mt = 0; mt < 4; ++mt) {
#pragma unroll
    for (int r = 0; r < 4; ++r) {
      const int i = mt * 16 + q * 4 + r;
      const unsigned long long mrow = msk[i];
      const int bi = (i >> 3) * 15 + (i & 7);
#pragma unroll
      for (int nt = 0; nt < 4; ++nt) {
        const int j = nt * 16 + mr;
        const int idx = bi + 112 - (j >> 3) * 15 - (j & 7);
        float val = sac[mt][nt][r] * 0.17677669529663687f + tbl[idx];
        float p = __expf(val);
        p = ((mrow >> j) & 1ull) ? p : 0.f;
        psum[mt][r] += p;
        Ps[i * 72 + j] = f2bf(p);
      }
    }
  }
  float inv[4][4];
#pragma unroll
  for (int mt = 0; mt < 4; ++mt)
#pragma unroll
    for (int r = 0; r < 4; ++r) {
      float s = psum[mt][r];
      s += __shfl_xor(s, 1, 64);
      s += __shfl_xor(s, 2, 64);
      s += __shfl_xor(s, 4, 64);
      s += __shfl_xor(s, 8, 64);
      inv[mt][r] = 1.f / s;
    }

  // ---- O = P.V ----
  floatx4 oac[4][2];
#pragma unroll
  for (int i = 0; i < 4; ++i)
#pragma unroll
    for (int j = 0; j < 2; ++j) oac[i][j] = floatx4{0.f, 0.f, 0.f, 0.f};
#pragma unroll
  for (int kk = 0; kk < 2; ++kk) {
    short8 ap[4], bv[2];
#pragma unroll
    for (int mt = 0; mt < 4; ++mt)
      ap[mt] = *(const short8*)(Ps + (mt * 16 + mr) * 72 + kk * 32 + q * 8);
#pragma unroll
    for (int nt = 0; nt < 2; ++nt)
      bv[nt] = *(const short8*)(Vt + (nt * 16 + mr) * 72 + kk * 32 + q * 8);
#pragma unroll
    for (int mt = 0; mt < 4; ++mt)
#pragma unroll
      for (int nt = 0; nt < 2; ++nt)
        oac[mt][nt] = __builtin_amdgcn_mfma_f32_16x16x32_bf16(ap[mt], bv[nt], oac[mt][nt], 0, 0, 0);
  }

  // ---- normalize + LDS round-trip -> vectorized store ----
#pragma unroll
  for (int mt = 0; mt < 4; ++mt)
#pragma unroll
    for (int nt = 0; nt < 2; ++nt)
#pragma unroll
      for (int r = 0; r < 4; ++r)
        Os[(mt * 16 + q * 4 + r) * 40 + nt * 16 + mr] = oac[mt][nt][r] * inv[mt][r];
  float ov[32];
#pragma unroll
  for (int c = 0; c < 8; ++c) {
    const int cc = c ^ (lane & 7);
    float4 t = *(const float4*)(Os + lane * 40 + cc * 4);
    ov[cc * 4 + 0] = t.x; ov[cc * 4 + 1] = t.y;
    ov[cc * 4 + 2] = t.z; ov[cc * 4 + 3] = t.w;
  }
  uint4* o4 = (uint4*)(out + ((size_t)win * 64 + lane) * CDIM + head * 32);
#pragma unroll
  for (int i = 0; i < 4; ++i) {
    uint4 pk;
    pk.x = pack2(ov[i * 8 + 0], ov[i * 8 + 1]);
    pk.y = pack2(ov[i * 8 + 2], ov[i * 8 + 3]);
    pk.z = pack2(ov[i * 8 + 4], ov[i * 8 + 5]);
    pk.w = pack2(ov[i * 8 + 6], ov[i * 8 + 7]);
    o4[i] = pk;
  }
}

extern "C" void kernel_launch(void* const* d_in, const int* in_sizes, int n_in,
                              void* d_out, int out_size, void* d_ws, size_t ws_size,
                              hipStream_t stream) {
  const float* x = (const float*)d_in[0];
  const float* n1g = (const float*)d_in[1];
  const float* n1b = (const float*)d_in[2];
  const float* qkv_w = (const float*)d_in[3];
  const float* qkv_b = (const float*)d_in[4];
  const float* reltbl = (const float*)d_in[5];
  const float* proj_w = (const float*)d_in[6];
  const float* proj_b = (const float*)d_in[7];
  const float* n2g = (const float*)d_in[8];
  const float* n2b = (const float*)d_in[9];
  const float* fc1_w = (const float*)d_in[10];
  const float* fc1_b = (const float*)d_in[11];
  const float* fc2_w = (const float*)d_in[12];
  const float* fc2_b = (const float*)d_in[13];
  float* out = (float*)d_out;

  char* p = (char*)d_ws;
  bf16* w_qkv_t = (bf16*)p;  p += (size_t)442368 * 2;
  bf16* w_proj_t = (bf16*)p; p += (size_t)147456 * 2;
  bf16* w_fc1_t = (bf16*)p;  p += (size_t)589824 * 2;
  bf16* w_fc2_t = (bf16*)p;  p += (size_t)589824 * 2;
  bf16* bufA = (bf16*)p;     p += (size_t)12582912 * 2;
  bf16* qkvb = (bf16*)p;     p += (size_t)37748736 * 2;
  bf16* attno = (bf16*)p;    p += (size_t)12582912 * 2;
  float* x1 = (float*)p;     p += (size_t)12582912 * 4;
  bf16* hidden = qkvb;  // reuses dead qkv/attn regions

  k_convt<<<dim3((442368 + 255) / 256), dim3(256), 0, stream>>>(qkv_w, w_qkv_t, 384, 1152);
  k_convt<<<dim3((147456 + 255) / 256), dim3(256), 0, stream>>>(proj_w, w_proj_t, 384, 384);
  k_convt<<<dim3((589824 + 255) / 256), dim3(256), 0, stream>>>(fc1_w, w_fc1_t, 384, 1536);
  k_convt<<<dim3((589824 + 255) / 256), dim3(256), 0, stream>>>(fc2_w, w_fc2_t, 1536, 384);

  k_ln1<<<dim3(8192), dim3(256), 0, stream>>>(x, n1g, n1b, bufA);
  k_gemm<384, 0, 9><<<dim3(9 * 256), dim3(256), 0, stream>>>(bufA, w_qkv_t, qkv_b, nullptr, qkvb);
  k_attn<<<dim3(6144), dim3(64), 0, stream>>>(qkvb, reltbl, attno);
  k_gemm<384, 1, 3><<<dim3(3 * 256), dim3(256), 0, stream>>>(attno, w_proj_t, proj_b, x, x1);
  k_ln2<<<dim3(8192), dim3(256), 0, stream>>>(x1, n2g, n2b, bufA);
  k_gemm<384, 2, 12><<<dim3(12 * 256), dim3(256), 0, stream>>>(bufA, w_fc1_t, fc1_b, nullptr, hidden);
  k_gemm<1536, 3, 3><<<dim3(3 * 256), dim3(256), 0, stream>>>(hidden, w_fc2_t, fc2_b, x1, out);
}